// Round 2
// 20528.596 us; speedup vs baseline: 1.1749x; 1.1749x over previous
//
#include <hip/hip_runtime.h>

// ============================================================================
// Interactor (attention-gated LSTM), MI355X gfx950. FP32 I/O; bf16 MFMA inside.
// Round 5: identical algorithm to round 4 (coherent-traffic diet), plus a
// BOUNDED grid barrier: spins time out after ~ms and set a sticky 'dead' flag
// so the persistent kernel can never hard-hang the GPU (a deadlock now shows
// up as passed:false + counters instead of a killed container).
//  - h stored in MFMA-fragment order; P0 blocks stage a 16KB row-slice into
//    LDS with 8 coalesced coherent dwords/thread (was 10.2 MB/step of
//    scattered dword atomics -> 1.25 MB/step).
//  - W_hh / W_R fragments live in 64 VGPRs per wave (loop-invariant preload).
//  - batch-softmax without max-subtraction (betas bounded): P1 writes exp(b)
//    + 4-way partial atomic denominators; P2 reads 400 floats instead of the
//    5120-value beta broadcast (5.2 MB/step -> ~0.1 MB/step).
// ============================================================================

typedef unsigned short ushort_t;
typedef unsigned int uint_t;
typedef __attribute__((ext_vector_type(8))) short bf16x8;   // 8 x bf16
typedef __attribute__((ext_vector_type(4))) float f32x4;

#define MFMA_BF16 __builtin_amdgcn_mfma_f32_16x16x32_bf16

__device__ __forceinline__ float bf2f(ushort_t u) {
  return __builtin_bit_cast(float, (uint_t)u << 16);
}
__device__ __forceinline__ ushort_t f2bf(float f) {   // round-to-nearest-even
  uint_t u = __builtin_bit_cast(uint_t, f);
  u += 0x7FFFu + ((u >> 16) & 1u);
  return (ushort_t)(u >> 16);
}
__device__ __forceinline__ uint_t pk(float lo, float hi) {
  return (uint_t)f2bf(lo) | ((uint_t)f2bf(hi) << 16);
}
__device__ __forceinline__ void stage16(ushort_t* dst, const float* src) {
  float4 a = *(const float4*)src,     b = *(const float4*)(src + 4);
  float4 c = *(const float4*)(src + 8), d = *(const float4*)(src + 12);
  uint4 lo = { pk(a.x,a.y), pk(a.z,a.w), pk(b.x,b.y), pk(b.z,b.w) };
  uint4 hi = { pk(c.x,c.y), pk(c.z,c.w), pk(d.x,d.y), pk(d.z,d.w) };
  *(uint4*)dst = lo; *(uint4*)(dst + 8) = hi;
}
__device__ __forceinline__ bf16x8 cvt8(const float* src) {
  float4 a = *(const float4*)src, b = *(const float4*)(src + 4);
  uint4 u = { pk(a.x,a.y), pk(a.z,a.w), pk(b.x,b.y), pk(b.z,b.w) };
  return __builtin_bit_cast(bf16x8, u);
}
__device__ __forceinline__ float tanh_(float x) {
  float e = __expf(2.f * x);
  return 1.f - 2.f * __builtin_amdgcn_rcpf(e + 1.f);
}
__device__ __forceinline__ float sigm_(float x) {
  return __builtin_amdgcn_rcpf(1.f + __expf(-x));
}

// -------- device-coherent (MALL) accessors: no fences, no cache walks -------
__device__ __forceinline__ float ldcg_f(const float* p) {
  return __hip_atomic_load(p, __ATOMIC_RELAXED, __HIP_MEMORY_SCOPE_AGENT);
}
__device__ __forceinline__ void stcg_f(float* p, float v) {
  __hip_atomic_store(p, v, __ATOMIC_RELAXED, __HIP_MEMORY_SCOPE_AGENT);
}
__device__ __forceinline__ uint_t ldcg_u(const uint_t* p) {
  return __hip_atomic_load(p, __ATOMIC_RELAXED, __HIP_MEMORY_SCOPE_AGENT);
}
__device__ __forceinline__ void stcg_u(uint_t* p, uint_t v) {
  __hip_atomic_store(p, v, __ATOMIC_RELAXED, __HIP_MEMORY_SCOPE_AGENT);
}

// fp32 -> bf16 elementwise (n4 = count of float4 groups)
__global__ __launch_bounds__(256) void cvt_kernel(
    const float* __restrict__ in, ushort_t* __restrict__ out, int n4) {
  int i = blockIdx.x * blockDim.x + threadIdx.x;
  if (i < n4) {
    float4 v = ((const float4*)in)[i];
    uint2 r = { pk(v.x, v.y), pk(v.z, v.w) };
    ((uint2*)out)[i] = r;
  }
}

// W_ih[:, :1024] fp32 -> bf16 [2048][1024] (fallback path only)
__global__ __launch_bounds__(256) void cvt_wih_kernel(
    const float* __restrict__ in, ushort_t* __restrict__ out) {
  int i = blockIdx.x * blockDim.x + threadIdx.x;   // [0, 2048*256)
  int row = i >> 8, c = (i & 255) * 4;
  float4 v = *(const float4*)&in[(size_t)row * 1536 + c];
  uint2 r = { pk(v.x, v.y), pk(v.z, v.w) };
  *(uint2*)&out[(size_t)row * 1024 + c] = r;
}

// ---------------------------------------------------------------------------
// C = A*W^T (+bias), A:[MxK] fp32 (lda), W:[NxK] fp32 (ldw), out bf16 [..xldo].
// tmaj: output row remap row -> (row&511)*64 + (row>>9)  (time-major (t,b)).
// ---------------------------------------------------------------------------
__global__ __launch_bounds__(256) void gemm_bt(
    const float* __restrict__ A, int lda,
    const float* __restrict__ W, int ldw,
    const float* __restrict__ bias1,
    ushort_t* __restrict__ out, int ldo, int K, int tmaj)
{
  __shared__ __align__(16) ushort_t sA[128][32];
  __shared__ __align__(16) ushort_t sW[128][32];
  const int tid = threadIdx.x;
  const int col0 = blockIdx.x * 128, row0 = blockIdx.y * 128;
  const int lane = tid & 63, wv = tid >> 6;
  const int wr = (wv & 1) * 64, wc = (wv >> 1) * 64;
  const int fr = lane & 15, quad = lane >> 4;
  const int sr = tid >> 1, skk = (tid & 1) * 16;
  f32x4 acc[4][4] = {};
  for (int k0 = 0; k0 < K; k0 += 32) {
    stage16(&sA[sr][skk], &A[(size_t)(row0 + sr) * lda + k0 + skk]);
    stage16(&sW[sr][skk], &W[(size_t)(col0 + sr) * ldw + k0 + skk]);
    __syncthreads();
    bf16x8 af[4], wf[4];
    #pragma unroll
    for (int mt = 0; mt < 4; ++mt) af[mt] = *(const bf16x8*)&sA[wr + mt*16 + fr][quad*8];
    #pragma unroll
    for (int nt = 0; nt < 4; ++nt) wf[nt] = *(const bf16x8*)&sW[wc + nt*16 + fr][quad*8];
    #pragma unroll
    for (int mt = 0; mt < 4; ++mt)
      #pragma unroll
      for (int nt = 0; nt < 4; ++nt)
        acc[mt][nt] = MFMA_BF16(af[mt], wf[nt], acc[mt][nt], 0, 0, 0);
    __syncthreads();
  }
  #pragma unroll
  for (int nt = 0; nt < 4; ++nt) {
    int col = col0 + wc + nt*16 + fr;
    float bs = bias1 ? bias1[col] : 0.f;
    #pragma unroll
    for (int mt = 0; mt < 4; ++mt)
      #pragma unroll
      for (int r = 0; r < 4; ++r) {
        int row = row0 + wr + mt*16 + quad*4 + r;
        int orow = tmaj ? ((row & 511) * 64 + (row >> 9)) : row;
        out[(size_t)orow * ldo + col] = f2bf(acc[mt][nt][r] + bs);
      }
  }
}

// ---------------------------------------------------------------------------
// Fence-free grid barrier with BOUNDED spins. bar layout (uints):
//   [0..231]  8 group counters, 128B apart
//   [256]     root counter
//   [288]     generation
//   [320]     sticky 'dead' flag (timeout tripwire)
// On timeout (~10k sleep iters, only reachable on a true deadlock) the dead
// flag is set; every subsequent grid_sync returns immediately -> the kernel
// terminates with wrong results instead of hanging the device.
// ---------------------------------------------------------------------------
__device__ __forceinline__ void spin_gen(unsigned* gen, unsigned g, unsigned* dead) {
  int n = 0;
  while (__hip_atomic_load(gen, __ATOMIC_RELAXED, __HIP_MEMORY_SCOPE_AGENT) == g) {
    __builtin_amdgcn_s_sleep(8);
    if (++n > 10000) {
      __hip_atomic_store(dead, 1u, __ATOMIC_RELAXED, __HIP_MEMORY_SCOPE_AGENT);
      break;
    }
    if ((n & 511) == 0 &&
        __hip_atomic_load(dead, __ATOMIC_RELAXED, __HIP_MEMORY_SCOPE_AGENT) != 0u)
      break;
  }
}

__device__ __forceinline__ void grid_sync(unsigned* bar) {
  __syncthreads();
  if (threadIdx.x == 0) {
    unsigned* gen  = bar + 288;
    unsigned* dead = bar + 320;
    if (__hip_atomic_load(dead, __ATOMIC_RELAXED, __HIP_MEMORY_SCOPE_AGENT) == 0u) {
      unsigned g = __hip_atomic_load(gen, __ATOMIC_RELAXED, __HIP_MEMORY_SCOPE_AGENT);
      unsigned grp = blockIdx.x & 7u;
      unsigned old = __hip_atomic_fetch_add(bar + grp * 32, 1u,
                        __ATOMIC_RELAXED, __HIP_MEMORY_SCOPE_AGENT);
      if (old == 31u) {
        unsigned r = __hip_atomic_fetch_add(bar + 256, 1u,
                        __ATOMIC_RELAXED, __HIP_MEMORY_SCOPE_AGENT);
        if (r == 7u) {
          #pragma unroll
          for (int i = 0; i < 8; ++i)
            __hip_atomic_store(bar + i * 32, 0u, __ATOMIC_RELAXED, __HIP_MEMORY_SCOPE_AGENT);
          __hip_atomic_store(bar + 256, 0u, __ATOMIC_RELAXED, __HIP_MEMORY_SCOPE_AGENT);
          __builtin_amdgcn_s_waitcnt(0);     // resets globally ack'd before flip
          __hip_atomic_store(gen, g + 1u, __ATOMIC_RELAXED, __HIP_MEMORY_SCOPE_AGENT);
        } else {
          spin_gen(gen, g, dead);
        }
      } else {
        spin_gen(gen, g, dead);
      }
    }
  }
  __syncthreads();
}

struct LoopArgs {
  const ushort_t *Sproj, *Vproj, *G, *Xproj;        // precomputed bf16
  const ushort_t *WRb, *Whhb, *Wihb;                // bf16 weights
  const float *bR, *Ww, *bih, *bhh, *hv;            // fp32 inputs
  float *ru, *gpre, *expb, *s4;                     // cross-block scratch
  uint_t *hrep;                                     // h, repacked MFMA-frag layout
  unsigned *bar;
  float *out;                                       // (B,T,HI) fp32
};

// h repacked layout (bf16 packed in dwords):
//   element (batch r, col c):  mt=r>>4, row=r&15, kc=c>>5, quad=(c>>3)&3, e=c&7
//   dword = ((mt*16+kc)*4+quad)*64 + row*4 + (e>>1)
// => per-mt slice is a contiguous 16 KB region; a wave's MFMA A-frag read for
//    (kc,quad,fr) is 16B contiguous, and a block's stage is 8 coalesced
//    dwords/thread.

// 256 blocks x 512 threads, persistent over T=512 steps, 3 barriers/step.
__global__ __launch_bounds__(512, 2) void loop_kernel(LoopArgs p) {
  const int blk = blockIdx.x, tid = threadIdx.x;
  const int lane = tid & 63, wv = tid >> 6;
  const int fr = lane & 15, quad = lane >> 4;
  const int b4 = blk >> 2, q4 = blk & 3;

  __shared__ __align__(16) uint_t sH[4096];         // 16 KB staged h row-slice
  __shared__ __align__(16) float s_ru[512];
  __shared__ __align__(16) float s_ww[512];
  __shared__ float s_alpha[80];
  __shared__ float s_gates[512];
  __shared__ float s_h[128];

  s_ww[tid] = p.Ww[tid];
  float c_reg = 0.f;                                // cell state: register-resident

  // ---- loop-invariant weight fragments -> 64 VGPRs per wave ---------------
  const bool isG = (blk < 64);
  const bool isR = (blk >= 64) && (blk < 80);
  int mt = 0, ncol = 0;
  bf16x8 wfr[16];
  if (isG) {                                        // gates: 64 blk = 4 mt x 16 cg
    mt = blk & 3;
    ncol = (blk >> 2) * 128 + wv * 16 + fr;         // [0,2048)
    #pragma unroll
    for (int kc = 0; kc < 16; ++kc)
      wfr[kc] = *(const bf16x8*)&p.Whhb[(size_t)ncol * 512 + kc * 32 + quad * 8];
  } else if (isR) {                                 // r_u: 16 blk = 4 mt x 4 cg
    int w = blk - 64;
    mt = w & 3;
    ncol = (w >> 2) * 128 + wv * 16 + fr;           // [0,512)
    #pragma unroll
    for (int kc = 0; kc < 16; ++kc)
      wfr[kc] = *(const bf16x8*)&p.WRb[(size_t)ncol * 512 + kc * 32 + quad * 8];
  }

  for (int t = 0; t < 512; ++t) {
    // ====== P0: gates-hh MFMA (blk<64) + r_u MFMA (blk 64..79) =============
    if (isG || isR) {
      f32x4 acc = {};
      if (t) {                                      // t=0: h=0, skip the read
        // cooperative coherent stage: 16 KB slice, 8 coalesced dwords/thread
        const uint_t* src = p.hrep + mt * 4096;
        uint_t hst[8];
        #pragma unroll
        for (int i = 0; i < 8; ++i) hst[i] = ldcg_u(src + i * 512 + tid);
        #pragma unroll
        for (int i = 0; i < 8; ++i) sH[i * 512 + tid] = hst[i];
        __syncthreads();
        #pragma unroll
        for (int kc = 0; kc < 16; ++kc) {           // conflict-free ds_read_b128
          bf16x8 af = *(const bf16x8*)&sH[kc * 256 + quad * 64 + fr * 4];
          acc = MFMA_BF16(af, wfr[kc], acc, 0, 0, 0);
        }
      }
      if (isG) {
        float bias = p.bih[ncol] + p.bhh[ncol];
        if (p.Xproj) {                              // hoisted X-projection
          #pragma unroll
          for (int r = 0; r < 4; ++r) {
            int b = mt * 16 + quad * 4 + r;
            float xv = bf2f(p.Xproj[(size_t)t * 131072 + b * 2048 + ncol]);
            stcg_f(&p.gpre[b * 2048 + ncol], acc[r] + xv + bias);
          }
        } else {                                    // in-loop X (fallback)
          f32x4 acc2 = {};
          int mrow = mt * 16 + fr;
          #pragma unroll
          for (int kc = 0; kc < 32; ++kc) {
            int ko = kc * 32 + quad * 8;
            bf16x8 af2 = cvt8(&p.hv[((size_t)mrow * 512 + t) * 1024 + ko]);
            bf16x8 wf2 = *(const bf16x8*)&p.Wihb[(size_t)ncol * 1024 + ko];
            acc2 = MFMA_BF16(af2, wf2, acc2, 0, 0, 0);
          }
          #pragma unroll
          for (int r = 0; r < 4; ++r) {
            int b = mt * 16 + quad * 4 + r;
            stcg_f(&p.gpre[b * 2048 + ncol], acc[r] + acc2[r] + bias);
          }
        }
      } else {
        float br = p.bR[ncol];
        #pragma unroll
        for (int r = 0; r < 4; ++r) {
          int b = mt * 16 + quad * 4 + r;
          float vv = bf2f(p.Vproj[(size_t)t * 32768 + b * 512 + ncol]);
          stcg_f(&p.ru[b * 512 + ncol], acc[r] + br + vv);
        }
      }
    }
    grid_sync(p.bar);

    // ====== P1: attention beta -> exp + partial denominators ===============
    s_ru[tid] = ldcg_f(&p.ru[b4 * 512 + tid]);
    __syncthreads();
    #pragma unroll
    for (int rr = 0; rr < 3; ++rr) {
      int nl = wv + 8 * rr;
      if (nl < 20) {
        int n = q4 * 20 + nl;
        uint4 sv = *(const uint4*)&p.Sproj[((size_t)(b4 * 80 + n)) * 512 + lane * 8];
        float4 r0 = *(const float4*)&s_ru[lane * 8];
        float4 r1 = *(const float4*)&s_ru[lane * 8 + 4];
        float4 w0 = *(const float4*)&s_ww[lane * 8];
        float4 w1 = *(const float4*)&s_ww[lane * 8 + 4];
        float a = 0.f;
        a += tanh_(bf2f((ushort_t)(sv.x & 0xFFFF)) + r0.x) * w0.x;
        a += tanh_(bf2f((ushort_t)(sv.x >> 16))    + r0.y) * w0.y;
        a += tanh_(bf2f((ushort_t)(sv.y & 0xFFFF)) + r0.z) * w0.z;
        a += tanh_(bf2f((ushort_t)(sv.y >> 16))    + r0.w) * w0.w;
        a += tanh_(bf2f((ushort_t)(sv.z & 0xFFFF)) + r1.x) * w1.x;
        a += tanh_(bf2f((ushort_t)(sv.z >> 16))    + r1.y) * w1.y;
        a += tanh_(bf2f((ushort_t)(sv.w & 0xFFFF)) + r1.z) * w1.z;
        a += tanh_(bf2f((ushort_t)(sv.w >> 16))    + r1.w) * w1.w;
        #pragma unroll
        for (int off = 32; off > 0; off >>= 1) a += __shfl_xor(a, off, 64);
        if (lane == 0) {
          // |beta| <= sum|W_w| ~ 8 -> exp is safe without max-subtraction
          float e = __expf(a);
          stcg_f(&p.expb[b4 * 80 + n], e);
          __hip_atomic_fetch_add(&p.s4[(t & 1) * 320 + (b4 & 3) * 80 + n], e,
                                 __ATOMIC_RELAXED, __HIP_MEMORY_SCOPE_AGENT);
        }
      }
    }
    grid_sync(p.bar);

    // ====== P2: alpha + G-sum + LSTM pointwise =============================
    if (tid < 80) {
      const float* sc = p.s4 + (t & 1) * 320;
      float s = ldcg_f(sc + tid) + ldcg_f(sc + 80 + tid) +
                ldcg_f(sc + 160 + tid) + ldcg_f(sc + 240 + tid);
      float e = ldcg_f(&p.expb[b4 * 80 + tid]);
      s_alpha[tid] = e * __builtin_amdgcn_rcpf(s);
    }
    if (blk == 0 && tid < 320)                      // zero next-parity denoms
      stcg_f(&p.s4[((t + 1) & 1) * 320 + tid], 0.f);
    __syncthreads();
    {
      int gg = tid >> 7, jj = tid & 127;
      int k = gg * 512 + q4 * 128 + jj;
      const ushort_t* Gp = &p.G[(size_t)b4 * 80 * 2048 + k];
      float v0 = 0, v1 = 0, v2 = 0, v3 = 0;
      for (int n = 0; n < 80; n += 4) {
        v0 += s_alpha[n]     * bf2f(Gp[(size_t)n * 2048]);
        v1 += s_alpha[n + 1] * bf2f(Gp[(size_t)(n + 1) * 2048]);
        v2 += s_alpha[n + 2] * bf2f(Gp[(size_t)(n + 2) * 2048]);
        v3 += s_alpha[n + 3] * bf2f(Gp[(size_t)(n + 3) * 2048]);
      }
      s_gates[tid] = ldcg_f(&p.gpre[b4 * 2048 + k]) + ((v0 + v1) + (v2 + v3));
    }
    __syncthreads();
    if (tid < 128) {
      int j = q4 * 128 + tid;
      float ig = sigm_(s_gates[tid]);
      float fg = sigm_(s_gates[128 + tid]);
      float g_ = tanh_(s_gates[256 + tid]);
      float og = sigm_(s_gates[384 + tid]);
      float cn = fg * c_reg + ig * g_;
      c_reg = cn;
      float hn = og * tanh_(cn);
      s_h[tid] = hn;
      p.out[((size_t)b4 * 512 + t) * 512 + j] = hn;
    }
    __syncthreads();
    if (tid < 64) {                                 // h -> repacked frag layout
      int c = q4 * 128 + tid * 2;                   // global col (even)
      int kc = c >> 5, qd = (c >> 3) & 3, e2 = (c & 7) >> 1;
      int dw = (((b4 >> 4) * 16 + kc) * 4 + qd) * 64 + (b4 & 15) * 4 + e2;
      stcg_u(&p.hrep[dw], pk(s_h[tid * 2], s_h[tid * 2 + 1]));
    }
    grid_sync(p.bar);
  }
}

// ===========================================================================
extern "C" void kernel_launch(void* const* d_in, const int* in_sizes, int n_in,
                              void* d_out, int out_size, void* d_ws, size_t ws_size,
                              hipStream_t stream) {
  (void)in_sizes; (void)n_in; (void)out_size;
  const float* hv   = (const float*)d_in[0];
  const float* hs   = (const float*)d_in[1];
  const float* W_S  = (const float*)d_in[2];
  const float* b_S  = (const float*)d_in[3];
  const float* W_V  = (const float*)d_in[4];
  const float* b_V  = (const float*)d_in[5];
  const float* W_R  = (const float*)d_in[6];
  const float* b_R  = (const float*)d_in[7];
  const float* W_w  = (const float*)d_in[8];
  /* d_in[9] = b_w: dropped (softmax shift-invariance) */
  const float* W_ih = (const float*)d_in[10];
  const float* b_ih = (const float*)d_in[11];
  const float* W_hh = (const float*)d_in[12];
  const float* b_hh = (const float*)d_in[13];

  char* ws = (char*)d_ws;
  unsigned long long off = 0;
  auto alloc = [&](unsigned long long bytes) {
    unsigned long long pp = off; off += (bytes + 255ull) & ~255ull; return pp;
  };
  ushort_t* Sproj = (ushort_t*)(ws + alloc(5120ull * 512 * 2));
  ushort_t* Vproj = (ushort_t*)(ws + alloc(512ull * 64 * 512 * 2));   // time-major
  ushort_t* G     = (ushort_t*)(ws + alloc(5120ull * 2048 * 2));
  ushort_t* WRb   = (ushort_t*)(ws + alloc(512ull * 512 * 2));
  ushort_t* Whhb  = (ushort_t*)(ws + alloc(2048ull * 512 * 2));
  float*    ru    = (float*)(ws + alloc(64ull * 512 * 4));
  float*    gpre  = (float*)(ws + alloc(64ull * 2048 * 4));
  float*    expb  = (float*)(ws + alloc(64ull * 80 * 4));
  unsigned long long zoff = off;
  uint_t*   hrep  = (uint_t*)(ws + alloc(16384ull * 4));
  float*    s4    = (float*)(ws + alloc(2ull * 4 * 80 * 4));
  unsigned* bar   = (unsigned*)(ws + alloc(2048));
  unsigned long long zsize = off - zoff;
  unsigned long long tail = off;                    // Xproj or Wihb goes here
  bool precX = ws_size >= tail + 512ull * 64 * 2048 * 2 + 4096;
  ushort_t* Xproj = precX ? (ushort_t*)(ws + tail) : nullptr;
  ushort_t* Wihb  = precX ? nullptr : (ushort_t*)(ws + tail);

  cvt_kernel<<<256,  256, 0, stream>>>(W_R,  WRb,  512 * 512 / 4);
  cvt_kernel<<<1024, 256, 0, stream>>>(W_hh, Whhb, 2048 * 512 / 4);
  if (!precX) cvt_wih_kernel<<<2048, 256, 0, stream>>>(W_ih, Wihb);

  // S_proj = h_s.W_S^T + b_S            (5120 x 512, K=512), row-major
  gemm_bt<<<dim3(4, 40), 256, 0, stream>>>(hs, 512, W_S, 512, b_S, Sproj, 512, 512, 0);
  // V_proj = h_v.W_V^T + b_V            (32768 x 512, K=1024), time-major
  gemm_bt<<<dim3(4, 256), 256, 0, stream>>>(hv, 1024, W_V, 1024, b_V, Vproj, 512, 1024, 1);
  // G = h_s.(W_ih[:,1024:])^T           (5120 x 2048, K=512), row-major
  gemm_bt<<<dim3(16, 40), 256, 0, stream>>>(hs, 512, W_ih + 1024, 1536, nullptr, G, 2048, 512, 0);
  // Xproj = h_v.(W_ih[:, :1024])^T      (32768 x 2048, K=1024), time-major
  if (precX)
    gemm_bt<<<dim3(16, 256), 256, 0, stream>>>(hv, 1024, W_ih, 1536, nullptr, Xproj, 2048, 1024, 1);

  hipMemsetAsync(ws + zoff, 0, (size_t)zsize, stream);   // hrep, s4, barrier = 0

  LoopArgs la;
  la.Sproj = Sproj; la.Vproj = Vproj; la.G = G; la.Xproj = Xproj;
  la.WRb = WRb; la.Whhb = Whhb; la.Wihb = Wihb;
  la.bR = b_R; la.Ww = W_w; la.bih = b_ih; la.bhh = b_hh; la.hv = hv;
  la.ru = ru; la.gpre = gpre; la.expb = expb; la.s4 = s4;
  la.hrep = hrep; la.bar = bar; la.out = (float*)d_out;
  loop_kernel<<<256, 512, 0, stream>>>(la);
}

// Round 3
// 13165.126 us; speedup vs baseline: 1.8320x; 1.5593x over previous
//
#include <hip/hip_runtime.h>

// ============================================================================
// Interactor (attention-gated LSTM), MI355X gfx950. FP32 I/O; bf16 MFMA inside.
// Round 6: kill the G array (was 21 MB/step of L2 misses = the whole step).
//   H_t_s part of gates computed as (sum_n alpha*h_s) . Wih_s^T per step:
//   - hsb: bf16 h_s (64x80x512, 5 MB), L2-resident per-XCD slices.
//   - Wq:  bf16 Wih_s pre-packed [q4][jc][kk][8] (2 MB), coalesced gemv reads.
//   - XCD-friendly (b4,q4) remap: b4=(blk&7)*8+(blk>>5), q4=(blk>>3)&3 ->
//     per-XCD residency: 8 hsb slices (640 KB) + Wq (2 MB) + Sproj (640 KB).
//   P2: alpha -> Hs[j] (80 FMA/thread) -> gemv (512 FMA/thread, LDS-broadcast
//   Hs) -> + gpre -> pointwise. G GEMM dropped from precompute.
// Bounded grid barrier kept (deadlock -> sticky dead flag, never hangs).
// ============================================================================

typedef unsigned short ushort_t;
typedef unsigned int uint_t;
typedef __attribute__((ext_vector_type(8))) short bf16x8;   // 8 x bf16
typedef __attribute__((ext_vector_type(4))) float f32x4;

#define MFMA_BF16 __builtin_amdgcn_mfma_f32_16x16x32_bf16

__device__ __forceinline__ float bf2f(ushort_t u) {
  return __builtin_bit_cast(float, (uint_t)u << 16);
}
__device__ __forceinline__ ushort_t f2bf(float f) {   // round-to-nearest-even
  uint_t u = __builtin_bit_cast(uint_t, f);
  u += 0x7FFFu + ((u >> 16) & 1u);
  return (ushort_t)(u >> 16);
}
__device__ __forceinline__ uint_t pk(float lo, float hi) {
  return (uint_t)f2bf(lo) | ((uint_t)f2bf(hi) << 16);
}
__device__ __forceinline__ void stage16(ushort_t* dst, const float* src) {
  float4 a = *(const float4*)src,     b = *(const float4*)(src + 4);
  float4 c = *(const float4*)(src + 8), d = *(const float4*)(src + 12);
  uint4 lo = { pk(a.x,a.y), pk(a.z,a.w), pk(b.x,b.y), pk(b.z,b.w) };
  uint4 hi = { pk(c.x,c.y), pk(c.z,c.w), pk(d.x,d.y), pk(d.z,d.w) };
  *(uint4*)dst = lo; *(uint4*)(dst + 8) = hi;
}
__device__ __forceinline__ bf16x8 cvt8(const float* src) {
  float4 a = *(const float4*)src, b = *(const float4*)(src + 4);
  uint4 u = { pk(a.x,a.y), pk(a.z,a.w), pk(b.x,b.y), pk(b.z,b.w) };
  return __builtin_bit_cast(bf16x8, u);
}
__device__ __forceinline__ float tanh_(float x) {
  float e = __expf(2.f * x);
  return 1.f - 2.f * __builtin_amdgcn_rcpf(e + 1.f);
}
__device__ __forceinline__ float sigm_(float x) {
  return __builtin_amdgcn_rcpf(1.f + __expf(-x));
}

// -------- device-coherent (MALL) accessors: no fences, no cache walks -------
__device__ __forceinline__ float ldcg_f(const float* p) {
  return __hip_atomic_load(p, __ATOMIC_RELAXED, __HIP_MEMORY_SCOPE_AGENT);
}
__device__ __forceinline__ void stcg_f(float* p, float v) {
  __hip_atomic_store(p, v, __ATOMIC_RELAXED, __HIP_MEMORY_SCOPE_AGENT);
}
__device__ __forceinline__ uint_t ldcg_u(const uint_t* p) {
  return __hip_atomic_load(p, __ATOMIC_RELAXED, __HIP_MEMORY_SCOPE_AGENT);
}
__device__ __forceinline__ void stcg_u(uint_t* p, uint_t v) {
  __hip_atomic_store(p, v, __ATOMIC_RELAXED, __HIP_MEMORY_SCOPE_AGENT);
}

// fp32 -> bf16 elementwise (n4 = count of float4 groups)
__global__ __launch_bounds__(256) void cvt_kernel(
    const float* __restrict__ in, ushort_t* __restrict__ out, int n4) {
  int i = blockIdx.x * blockDim.x + threadIdx.x;
  if (i < n4) {
    float4 v = ((const float4*)in)[i];
    uint2 r = { pk(v.x, v.y), pk(v.z, v.w) };
    ((uint2*)out)[i] = r;
  }
}

// W_ih[:, :1024] fp32 -> bf16 [2048][1024] (fallback path only)
__global__ __launch_bounds__(256) void cvt_wih_kernel(
    const float* __restrict__ in, ushort_t* __restrict__ out) {
  int i = blockIdx.x * blockDim.x + threadIdx.x;   // [0, 2048*256)
  int row = i >> 8, c = (i & 255) * 4;
  float4 v = *(const float4*)&in[(size_t)row * 1536 + c];
  uint2 r = { pk(v.x, v.y), pk(v.z, v.w) };
  *(uint2*)&out[(size_t)row * 1024 + c] = r;
}

// W_ih[:, 1024:1536] -> Wq[q4][jc][kk][8] bf16; thread k-row kk owns
// k = (kk>>7)*512 + q4*128 + (kk&127); element j = jc*8 + e.
__global__ __launch_bounds__(256) void cvt_wq_kernel(
    const float* __restrict__ W_ih, ushort_t* __restrict__ Wq) {
  int i = blockIdx.x * blockDim.x + threadIdx.x;   // [0, 262144)
  int half = i & 1, kk = (i >> 1) & 511, jc = (i >> 10) & 63, q4 = i >> 16;
  int k = (kk >> 7) * 512 + q4 * 128 + (kk & 127);
  int j = jc * 8 + half * 4;
  float4 v = *(const float4*)&W_ih[(size_t)k * 1536 + 1024 + j];
  uint2 r = { pk(v.x, v.y), pk(v.z, v.w) };
  *(uint2*)&Wq[((size_t)(q4 * 64 + jc) * 512 + kk) * 8 + half * 4] = r;
}

// ---------------------------------------------------------------------------
// C = A*W^T (+bias), A:[MxK] fp32 (lda), W:[NxK] fp32 (ldw), out bf16 [..xldo].
// tmaj: output row remap row -> (row&511)*64 + (row>>9)  (time-major (t,b)).
// ---------------------------------------------------------------------------
__global__ __launch_bounds__(256) void gemm_bt(
    const float* __restrict__ A, int lda,
    const float* __restrict__ W, int ldw,
    const float* __restrict__ bias1,
    ushort_t* __restrict__ out, int ldo, int K, int tmaj)
{
  __shared__ __align__(16) ushort_t sA[128][32];
  __shared__ __align__(16) ushort_t sW[128][32];
  const int tid = threadIdx.x;
  const int col0 = blockIdx.x * 128, row0 = blockIdx.y * 128;
  const int lane = tid & 63, wv = tid >> 6;
  const int wr = (wv & 1) * 64, wc = (wv >> 1) * 64;
  const int fr = lane & 15, quad = lane >> 4;
  const int sr = tid >> 1, skk = (tid & 1) * 16;
  f32x4 acc[4][4] = {};
  for (int k0 = 0; k0 < K; k0 += 32) {
    stage16(&sA[sr][skk], &A[(size_t)(row0 + sr) * lda + k0 + skk]);
    stage16(&sW[sr][skk], &W[(size_t)(col0 + sr) * ldw + k0 + skk]);
    __syncthreads();
    bf16x8 af[4], wf[4];
    #pragma unroll
    for (int mt = 0; mt < 4; ++mt) af[mt] = *(const bf16x8*)&sA[wr + mt*16 + fr][quad*8];
    #pragma unroll
    for (int nt = 0; nt < 4; ++nt) wf[nt] = *(const bf16x8*)&sW[wc + nt*16 + fr][quad*8];
    #pragma unroll
    for (int mt = 0; mt < 4; ++mt)
      #pragma unroll
      for (int nt = 0; nt < 4; ++nt)
        acc[mt][nt] = MFMA_BF16(af[mt], wf[nt], acc[mt][nt], 0, 0, 0);
    __syncthreads();
  }
  #pragma unroll
  for (int nt = 0; nt < 4; ++nt) {
    int col = col0 + wc + nt*16 + fr;
    float bs = bias1 ? bias1[col] : 0.f;
    #pragma unroll
    for (int mt = 0; mt < 4; ++mt)
      #pragma unroll
      for (int r = 0; r < 4; ++r) {
        int row = row0 + wr + mt*16 + quad*4 + r;
        int orow = tmaj ? ((row & 511) * 64 + (row >> 9)) : row;
        out[(size_t)orow * ldo + col] = f2bf(acc[mt][nt][r] + bs);
      }
  }
}

// ---------------------------------------------------------------------------
// Fence-free grid barrier with BOUNDED spins (sticky dead flag on timeout).
// ---------------------------------------------------------------------------
__device__ __forceinline__ void spin_gen(unsigned* gen, unsigned g, unsigned* dead) {
  int n = 0;
  while (__hip_atomic_load(gen, __ATOMIC_RELAXED, __HIP_MEMORY_SCOPE_AGENT) == g) {
    __builtin_amdgcn_s_sleep(8);
    if (++n > 10000) {
      __hip_atomic_store(dead, 1u, __ATOMIC_RELAXED, __HIP_MEMORY_SCOPE_AGENT);
      break;
    }
    if ((n & 511) == 0 &&
        __hip_atomic_load(dead, __ATOMIC_RELAXED, __HIP_MEMORY_SCOPE_AGENT) != 0u)
      break;
  }
}

__device__ __forceinline__ void grid_sync(unsigned* bar) {
  __syncthreads();
  if (threadIdx.x == 0) {
    unsigned* gen  = bar + 288;
    unsigned* dead = bar + 320;
    if (__hip_atomic_load(dead, __ATOMIC_RELAXED, __HIP_MEMORY_SCOPE_AGENT) == 0u) {
      unsigned g = __hip_atomic_load(gen, __ATOMIC_RELAXED, __HIP_MEMORY_SCOPE_AGENT);
      unsigned grp = blockIdx.x & 7u;
      unsigned old = __hip_atomic_fetch_add(bar + grp * 32, 1u,
                        __ATOMIC_RELAXED, __HIP_MEMORY_SCOPE_AGENT);
      if (old == 31u) {
        unsigned r = __hip_atomic_fetch_add(bar + 256, 1u,
                        __ATOMIC_RELAXED, __HIP_MEMORY_SCOPE_AGENT);
        if (r == 7u) {
          #pragma unroll
          for (int i = 0; i < 8; ++i)
            __hip_atomic_store(bar + i * 32, 0u, __ATOMIC_RELAXED, __HIP_MEMORY_SCOPE_AGENT);
          __hip_atomic_store(bar + 256, 0u, __ATOMIC_RELAXED, __HIP_MEMORY_SCOPE_AGENT);
          __builtin_amdgcn_s_waitcnt(0);     // resets globally ack'd before flip
          __hip_atomic_store(gen, g + 1u, __ATOMIC_RELAXED, __HIP_MEMORY_SCOPE_AGENT);
        } else {
          spin_gen(gen, g, dead);
        }
      } else {
        spin_gen(gen, g, dead);
      }
    }
  }
  __syncthreads();
}

struct LoopArgs {
  const ushort_t *Sproj, *Vproj, *Xproj;            // precomputed bf16
  const ushort_t *WRb, *Whhb, *Wihb;                // bf16 weights
  const ushort_t *hsb, *Wq;                         // bf16 h_s + packed Wih_s
  const float *bR, *Ww, *bih, *bhh, *hv;            // fp32 inputs
  float *ru, *gpre, *expb, *s4;                     // cross-block scratch
  uint_t *hbfd;                                     // (unused name kept) -- hrep
  unsigned *bar;
  float *out;                                       // (B,T,HI) fp32
};

// h repacked layout (bf16 packed in dwords):
//   element (batch r, col c):  mt=r>>4, row=r&15, kc=c>>5, quad=(c>>3)&3, e=c&7
//   dword = ((mt*16+kc)*4+quad)*64 + row*4 + (e>>1)

// 256 blocks x 512 threads, persistent over T=512 steps, 3 barriers/step.
__global__ __launch_bounds__(512, 2) void loop_kernel(LoopArgs p) {
  const int blk = blockIdx.x, tid = threadIdx.x;
  const int lane = tid & 63, wv = tid >> 6;
  const int fr = lane & 15, quad = lane >> 4;
  // XCD-friendly remap: XCD = blk%8 hosts b4 in {8*(blk&7) .. +8} only.
  const int b4 = (blk & 7) * 8 + (blk >> 5);
  const int q4 = (blk >> 3) & 3;

  __shared__ __align__(16) uint_t sH[4096];         // 16 KB staged h row-slice
  __shared__ __align__(16) float s_ru[512];
  __shared__ __align__(16) float s_ww[512];
  __shared__ __align__(16) float s_hs[512];
  __shared__ float s_alpha[80];
  __shared__ float s_gates[512];
  __shared__ float s_h[128];

  s_ww[tid] = p.Ww[tid];
  float c_reg = 0.f;                                // cell state: register-resident

  // ---- loop-invariant weight fragments -> 64 VGPRs per wave ---------------
  const bool isG = (blk < 64);
  const bool isR = (blk >= 64) && (blk < 80);
  int mt = 0, ncol = 0;
  bf16x8 wfr[16];
  if (isG) {                                        // gates: 64 blk = 4 mt x 16 cg
    mt = blk & 3;
    ncol = (blk >> 2) * 128 + wv * 16 + fr;         // [0,2048)
    #pragma unroll
    for (int kc = 0; kc < 16; ++kc)
      wfr[kc] = *(const bf16x8*)&p.Whhb[(size_t)ncol * 512 + kc * 32 + quad * 8];
  } else if (isR) {                                 // r_u: 16 blk = 4 mt x 4 cg
    int w = blk - 64;
    mt = w & 3;
    ncol = (w >> 2) * 128 + wv * 16 + fr;           // [0,512)
    #pragma unroll
    for (int kc = 0; kc < 16; ++kc)
      wfr[kc] = *(const bf16x8*)&p.WRb[(size_t)ncol * 512 + kc * 32 + quad * 8];
  }

  for (int t = 0; t < 512; ++t) {
    // ====== P0: gates-hh MFMA (blk<64) + r_u MFMA (blk 64..79) =============
    if (isG || isR) {
      f32x4 acc = {};
      if (t) {                                      // t=0: h=0, skip the read
        // cooperative coherent stage: 16 KB slice, 8 coalesced dwords/thread
        const uint_t* src = p.hbfd + mt * 4096;
        uint_t hst[8];
        #pragma unroll
        for (int i = 0; i < 8; ++i) hst[i] = ldcg_u(src + i * 512 + tid);
        #pragma unroll
        for (int i = 0; i < 8; ++i) sH[i * 512 + tid] = hst[i];
        __syncthreads();
        #pragma unroll
        for (int kc = 0; kc < 16; ++kc) {           // conflict-free ds_read_b128
          bf16x8 af = *(const bf16x8*)&sH[kc * 256 + quad * 64 + fr * 4];
          acc = MFMA_BF16(af, wfr[kc], acc, 0, 0, 0);
        }
      }
      if (isG) {
        float bias = p.bih[ncol] + p.bhh[ncol];
        if (p.Xproj) {                              // hoisted X-projection
          #pragma unroll
          for (int r = 0; r < 4; ++r) {
            int b = mt * 16 + quad * 4 + r;
            float xv = bf2f(p.Xproj[(size_t)t * 131072 + b * 2048 + ncol]);
            stcg_f(&p.gpre[b * 2048 + ncol], acc[r] + xv + bias);
          }
        } else {                                    // in-loop X (fallback)
          f32x4 acc2 = {};
          int mrow = mt * 16 + fr;
          #pragma unroll
          for (int kc = 0; kc < 32; ++kc) {
            int ko = kc * 32 + quad * 8;
            bf16x8 af2 = cvt8(&p.hv[((size_t)mrow * 512 + t) * 1024 + ko]);
            bf16x8 wf2 = *(const bf16x8*)&p.Wihb[(size_t)ncol * 1024 + ko];
            acc2 = MFMA_BF16(af2, wf2, acc2, 0, 0, 0);
          }
          #pragma unroll
          for (int r = 0; r < 4; ++r) {
            int b = mt * 16 + quad * 4 + r;
            stcg_f(&p.gpre[b * 2048 + ncol], acc[r] + acc2[r] + bias);
          }
        }
      } else {
        float br = p.bR[ncol];
        #pragma unroll
        for (int r = 0; r < 4; ++r) {
          int b = mt * 16 + quad * 4 + r;
          float vv = bf2f(p.Vproj[(size_t)t * 32768 + b * 512 + ncol]);
          stcg_f(&p.ru[b * 512 + ncol], acc[r] + br + vv);
        }
      }
    }
    grid_sync(p.bar);

    // ====== P1: attention beta -> exp + partial denominators ===============
    s_ru[tid] = ldcg_f(&p.ru[b4 * 512 + tid]);
    __syncthreads();
    #pragma unroll
    for (int rr = 0; rr < 3; ++rr) {
      int nl = wv + 8 * rr;
      if (nl < 20) {
        int n = q4 * 20 + nl;
        uint4 sv = *(const uint4*)&p.Sproj[((size_t)(b4 * 80 + n)) * 512 + lane * 8];
        float4 r0 = *(const float4*)&s_ru[lane * 8];
        float4 r1 = *(const float4*)&s_ru[lane * 8 + 4];
        float4 w0 = *(const float4*)&s_ww[lane * 8];
        float4 w1 = *(const float4*)&s_ww[lane * 8 + 4];
        float a = 0.f;
        a += tanh_(bf2f((ushort_t)(sv.x & 0xFFFF)) + r0.x) * w0.x;
        a += tanh_(bf2f((ushort_t)(sv.x >> 16))    + r0.y) * w0.y;
        a += tanh_(bf2f((ushort_t)(sv.y & 0xFFFF)) + r0.z) * w0.z;
        a += tanh_(bf2f((ushort_t)(sv.y >> 16))    + r0.w) * w0.w;
        a += tanh_(bf2f((ushort_t)(sv.z & 0xFFFF)) + r1.x) * w1.x;
        a += tanh_(bf2f((ushort_t)(sv.z >> 16))    + r1.y) * w1.y;
        a += tanh_(bf2f((ushort_t)(sv.w & 0xFFFF)) + r1.z) * w1.z;
        a += tanh_(bf2f((ushort_t)(sv.w >> 16))    + r1.w) * w1.w;
        #pragma unroll
        for (int off = 32; off > 0; off >>= 1) a += __shfl_xor(a, off, 64);
        if (lane == 0) {
          // |beta| <= sum|W_w| ~ 8 -> exp is safe without max-subtraction
          float e = __expf(a);
          stcg_f(&p.expb[b4 * 80 + n], e);
          __hip_atomic_fetch_add(&p.s4[(t & 1) * 320 + (b4 & 3) * 80 + n], e,
                                 __ATOMIC_RELAXED, __HIP_MEMORY_SCOPE_AGENT);
        }
      }
    }
    grid_sync(p.bar);

    // ====== P2: alpha + Hs + gemv + LSTM pointwise =========================
    if (tid < 80) {
      const float* sc = p.s4 + (t & 1) * 320;
      float s = ldcg_f(sc + tid) + ldcg_f(sc + 80 + tid) +
                ldcg_f(sc + 160 + tid) + ldcg_f(sc + 240 + tid);
      float e = ldcg_f(&p.expb[b4 * 80 + tid]);
      s_alpha[tid] = e * __builtin_amdgcn_rcpf(s);
    }
    if (blk == 0 && tid < 320)                      // zero next-parity denoms
      stcg_f(&p.s4[((t + 1) & 1) * 320 + tid], 0.f);
    __syncthreads();
    {
      // Hs[tid] = sum_n alpha[n] * h_s[b4, n, tid]   (hsb: L2-resident slice)
      const ushort_t* hp = p.hsb + (size_t)b4 * 40960 + tid;
      float a0 = 0.f, a1 = 0.f;
      #pragma unroll 8
      for (int n = 0; n < 80; n += 2) {
        a0 += s_alpha[n]     * bf2f(hp[(size_t)n * 512]);
        a1 += s_alpha[n + 1] * bf2f(hp[(size_t)(n + 1) * 512]);
      }
      s_hs[tid] = a0 + a1;
    }
    __syncthreads();
    {
      // gemv: thread owns k = (tid>>7)*512 + q4*128 + (tid&127); 512-long dot
      // against LDS-broadcast Hs. Wq reads: 1 KB contiguous per wave per jc.
      const uint_t* wbase = (const uint_t*)p.Wq + ((size_t)q4 * 32768 + tid) * 4;
      float g2 = 0.f;
      #pragma unroll 4
      for (int jc = 0; jc < 64; ++jc) {
        uint4 w4 = *(const uint4*)(wbase + (size_t)jc * 2048);
        float4 h0 = *(const float4*)&s_hs[jc * 8];
        float4 h1 = *(const float4*)&s_hs[jc * 8 + 4];
        g2 += bf2f((ushort_t)(w4.x & 0xFFFFu)) * h0.x;
        g2 += bf2f((ushort_t)(w4.x >> 16))     * h0.y;
        g2 += bf2f((ushort_t)(w4.y & 0xFFFFu)) * h0.z;
        g2 += bf2f((ushort_t)(w4.y >> 16))     * h0.w;
        g2 += bf2f((ushort_t)(w4.z & 0xFFFFu)) * h1.x;
        g2 += bf2f((ushort_t)(w4.z >> 16))     * h1.y;
        g2 += bf2f((ushort_t)(w4.w & 0xFFFFu)) * h1.z;
        g2 += bf2f((ushort_t)(w4.w >> 16))     * h1.w;
      }
      int kown = (tid >> 7) * 512 + q4 * 128 + (tid & 127);
      s_gates[tid] = ldcg_f(&p.gpre[b4 * 2048 + kown]) + g2;
    }
    __syncthreads();
    if (tid < 128) {
      int j = q4 * 128 + tid;
      float ig = sigm_(s_gates[tid]);
      float fg = sigm_(s_gates[128 + tid]);
      float g_ = tanh_(s_gates[256 + tid]);
      float og = sigm_(s_gates[384 + tid]);
      float cn = fg * c_reg + ig * g_;
      c_reg = cn;
      float hn = og * tanh_(cn);
      s_h[tid] = hn;
      p.out[((size_t)b4 * 512 + t) * 512 + j] = hn;
    }
    __syncthreads();
    if (tid < 64) {                                 // h -> repacked frag layout
      int c = q4 * 128 + tid * 2;                   // global col (even)
      int kc = c >> 5, qd = (c >> 3) & 3, e2 = (c & 7) >> 1;
      int dw = (((b4 >> 4) * 16 + kc) * 4 + qd) * 64 + (b4 & 15) * 4 + e2;
      stcg_u(&p.hbfd[dw], pk(s_h[tid * 2], s_h[tid * 2 + 1]));
    }
    grid_sync(p.bar);
  }
}

// ===========================================================================
extern "C" void kernel_launch(void* const* d_in, const int* in_sizes, int n_in,
                              void* d_out, int out_size, void* d_ws, size_t ws_size,
                              hipStream_t stream) {
  (void)in_sizes; (void)n_in; (void)out_size;
  const float* hv   = (const float*)d_in[0];
  const float* hs   = (const float*)d_in[1];
  const float* W_S  = (const float*)d_in[2];
  const float* b_S  = (const float*)d_in[3];
  const float* W_V  = (const float*)d_in[4];
  const float* b_V  = (const float*)d_in[5];
  const float* W_R  = (const float*)d_in[6];
  const float* b_R  = (const float*)d_in[7];
  const float* W_w  = (const float*)d_in[8];
  /* d_in[9] = b_w: dropped (softmax shift-invariance) */
  const float* W_ih = (const float*)d_in[10];
  const float* b_ih = (const float*)d_in[11];
  const float* W_hh = (const float*)d_in[12];
  const float* b_hh = (const float*)d_in[13];

  char* ws = (char*)d_ws;
  unsigned long long off = 0;
  auto alloc = [&](unsigned long long bytes) {
    unsigned long long pp = off; off += (bytes + 255ull) & ~255ull; return pp;
  };
  ushort_t* Sproj = (ushort_t*)(ws + alloc(5120ull * 512 * 2));
  ushort_t* Vproj = (ushort_t*)(ws + alloc(512ull * 64 * 512 * 2));   // time-major
  ushort_t* hsb   = (ushort_t*)(ws + alloc(64ull * 80 * 512 * 2));
  ushort_t* Wq    = (ushort_t*)(ws + alloc(4ull * 512 * 512 * 2));
  ushort_t* WRb   = (ushort_t*)(ws + alloc(512ull * 512 * 2));
  ushort_t* Whhb  = (ushort_t*)(ws + alloc(2048ull * 512 * 2));
  float*    ru    = (float*)(ws + alloc(64ull * 512 * 4));
  float*    gpre  = (float*)(ws + alloc(64ull * 2048 * 4));
  float*    expb  = (float*)(ws + alloc(64ull * 80 * 4));
  unsigned long long zoff = off;
  uint_t*   hrep  = (uint_t*)(ws + alloc(16384ull * 4));
  float*    s4    = (float*)(ws + alloc(2ull * 4 * 80 * 4));
  unsigned* bar   = (unsigned*)(ws + alloc(2048));
  unsigned long long zsize = off - zoff;
  unsigned long long tail = off;                    // Xproj or Wihb goes here
  bool precX = ws_size >= tail + 512ull * 64 * 2048 * 2 + 4096;
  ushort_t* Xproj = precX ? (ushort_t*)(ws + tail) : nullptr;
  ushort_t* Wihb  = precX ? nullptr : (ushort_t*)(ws + tail);

  cvt_kernel<<<256,  256, 0, stream>>>(W_R,  WRb,  512 * 512 / 4);
  cvt_kernel<<<1024, 256, 0, stream>>>(W_hh, Whhb, 2048 * 512 / 4);
  cvt_kernel<<<2560, 256, 0, stream>>>(hs, hsb, 64 * 80 * 512 / 4);
  cvt_wq_kernel<<<1024, 256, 0, stream>>>(W_ih, Wq);
  if (!precX) cvt_wih_kernel<<<2048, 256, 0, stream>>>(W_ih, Wihb);

  // S_proj = h_s.W_S^T + b_S            (5120 x 512, K=512), row-major
  gemm_bt<<<dim3(4, 40), 256, 0, stream>>>(hs, 512, W_S, 512, b_S, Sproj, 512, 512, 0);
  // V_proj = h_v.W_V^T + b_V            (32768 x 512, K=1024), time-major
  gemm_bt<<<dim3(4, 256), 256, 0, stream>>>(hv, 1024, W_V, 1024, b_V, Vproj, 512, 1024, 1);
  // Xproj = h_v.(W_ih[:, :1024])^T      (32768 x 2048, K=1024), time-major
  if (precX)
    gemm_bt<<<dim3(16, 256), 256, 0, stream>>>(hv, 1024, W_ih, 1536, nullptr, Xproj, 2048, 1024, 1);

  hipMemsetAsync(ws + zoff, 0, (size_t)zsize, stream);   // hrep, s4, barrier = 0

  LoopArgs la;
  la.Sproj = Sproj; la.Vproj = Vproj; la.Xproj = Xproj;
  la.WRb = WRb; la.Whhb = Whhb; la.Wihb = Wihb;
  la.hsb = hsb; la.Wq = Wq;
  la.bR = b_R; la.Ww = W_w; la.bih = b_ih; la.bhh = b_hh; la.hv = hv;
  la.ru = ru; la.gpre = gpre; la.expb = expb; la.s4 = s4;
  la.hbfd = hrep; la.bar = bar; la.out = (float*)d_out;
  loop_kernel<<<256, 512, 0, stream>>>(la);
}

// Round 4
// 12409.475 us; speedup vs baseline: 1.9436x; 1.0609x over previous
//
#include <hip/hip_runtime.h>

// ============================================================================
// Interactor (attention-gated LSTM), MI355X gfx950. FP32 I/O; bf16 MFMA inside.
// Round 7: all-MFMA step with gate-owner blocks (kills the P2 scalar gemv:
// 4.3 us VALU + 131 MB/step Wq L2 stream + 20 MB/step hsb stream).
//   128 gate blocks own (mt: 16 batches) x (jt: 16 j-cols) x all 4 gate groups:
//     Phase A: hh-MFMA (acc stays in VGPRs; Whh frags preloaded, invariant)
//     Phase D: Hs-MFMA (Wq frags preloaded) + Xproj + bias + pointwise + c/h
//   16 ru blocks: r_u MFMA (WR frags preloaded) -> ru coherent.
//   Phase B (all): beta/exp/s4 (unchanged). Phase C (all): alpha + Hs slice
//     -> hsrep coherent in MFMA-frag layout (64 KB/step).
//   4 grid barriers/step (was 3) -- bounded spins, sticky dead flag.
// ============================================================================

typedef unsigned short ushort_t;
typedef unsigned int uint_t;
typedef __attribute__((ext_vector_type(8))) short bf16x8;   // 8 x bf16
typedef __attribute__((ext_vector_type(4))) float f32x4;

#define MFMA_BF16 __builtin_amdgcn_mfma_f32_16x16x32_bf16

__device__ __forceinline__ float bf2f(ushort_t u) {
  return __builtin_bit_cast(float, (uint_t)u << 16);
}
__device__ __forceinline__ ushort_t f2bf(float f) {   // round-to-nearest-even
  uint_t u = __builtin_bit_cast(uint_t, f);
  u += 0x7FFFu + ((u >> 16) & 1u);
  return (ushort_t)(u >> 16);
}
__device__ __forceinline__ uint_t pk(float lo, float hi) {
  return (uint_t)f2bf(lo) | ((uint_t)f2bf(hi) << 16);
}
__device__ __forceinline__ void stage16(ushort_t* dst, const float* src) {
  float4 a = *(const float4*)src,     b = *(const float4*)(src + 4);
  float4 c = *(const float4*)(src + 8), d = *(const float4*)(src + 12);
  uint4 lo = { pk(a.x,a.y), pk(a.z,a.w), pk(b.x,b.y), pk(b.z,b.w) };
  uint4 hi = { pk(c.x,c.y), pk(c.z,c.w), pk(d.x,d.y), pk(d.z,d.w) };
  *(uint4*)dst = lo; *(uint4*)(dst + 8) = hi;
}
__device__ __forceinline__ bf16x8 cvt8(const float* src) {
  float4 a = *(const float4*)src, b = *(const float4*)(src + 4);
  uint4 u = { pk(a.x,a.y), pk(a.z,a.w), pk(b.x,b.y), pk(b.z,b.w) };
  return __builtin_bit_cast(bf16x8, u);
}
__device__ __forceinline__ float tanh_(float x) {
  float e = __expf(2.f * x);
  return 1.f - 2.f * __builtin_amdgcn_rcpf(e + 1.f);
}
__device__ __forceinline__ float sigm_(float x) {
  return __builtin_amdgcn_rcpf(1.f + __expf(-x));
}

// -------- device-coherent (MALL) accessors ---------------------------------
__device__ __forceinline__ float ldcg_f(const float* p) {
  return __hip_atomic_load(p, __ATOMIC_RELAXED, __HIP_MEMORY_SCOPE_AGENT);
}
__device__ __forceinline__ void stcg_f(float* p, float v) {
  __hip_atomic_store(p, v, __ATOMIC_RELAXED, __HIP_MEMORY_SCOPE_AGENT);
}
__device__ __forceinline__ uint_t ldcg_u(const uint_t* p) {
  return __hip_atomic_load(p, __ATOMIC_RELAXED, __HIP_MEMORY_SCOPE_AGENT);
}
__device__ __forceinline__ void stcg_u(uint_t* p, uint_t v) {
  __hip_atomic_store(p, v, __ATOMIC_RELAXED, __HIP_MEMORY_SCOPE_AGENT);
}

// fp32 -> bf16 elementwise (n4 = count of float4 groups)
__global__ __launch_bounds__(256) void cvt_kernel(
    const float* __restrict__ in, ushort_t* __restrict__ out, int n4) {
  int i = blockIdx.x * blockDim.x + threadIdx.x;
  if (i < n4) {
    float4 v = ((const float4*)in)[i];
    uint2 r = { pk(v.x, v.y), pk(v.z, v.w) };
    ((uint2*)out)[i] = r;
  }
}

// ---------------------------------------------------------------------------
// Pack weight rows into per-tile MFMA B-fragment order:
//   out[(tile*KCT + kc)*512 + lane*8 + e] = src[row*ld + coff + kc*32 + (lane>>4)*8 + e]
//   row = mode ? (tile&3)*512 + (tile>>2)*16 + (lane&15) : tile*16 + (lane&15)
// lkc = log2(KCT). One thread packs 8 elements.
// ---------------------------------------------------------------------------
__global__ __launch_bounds__(256) void pack_frag_kernel(
    const float* __restrict__ src, int ld, int coff,
    ushort_t* __restrict__ out, int mode, int lkc) {
  size_t o = ((size_t)blockIdx.x * 256 + threadIdx.x) * 8;
  int lane = (int)((o >> 3) & 63);
  int kc   = (int)((o >> 9) & ((1u << lkc) - 1u));
  int tile = (int)(o >> (9 + lkc));
  int row  = mode ? ((tile & 3) * 512 + (tile >> 2) * 16 + (lane & 15))
                  : (tile * 16 + (lane & 15));
  int col  = kc * 32 + (lane >> 4) * 8;
  const float* s = &src[(size_t)row * ld + coff + col];
  float4 a = *(const float4*)s, b = *(const float4*)(s + 4);
  uint4 u = { pk(a.x,a.y), pk(a.z,a.w), pk(b.x,b.y), pk(b.z,b.w) };
  *(uint4*)&out[o] = u;
}

// ---------------------------------------------------------------------------
// C = A*W^T (+bias), A:[MxK] fp32 (lda), W:[NxK] fp32 (ldw), out bf16 [..xldo].
// tmaj: output row remap row -> (row&511)*64 + (row>>9)  (time-major (t,b)).
// ---------------------------------------------------------------------------
__global__ __launch_bounds__(256) void gemm_bt(
    const float* __restrict__ A, int lda,
    const float* __restrict__ W, int ldw,
    const float* __restrict__ bias1,
    ushort_t* __restrict__ out, int ldo, int K, int tmaj)
{
  __shared__ __align__(16) ushort_t sA[128][32];
  __shared__ __align__(16) ushort_t sW[128][32];
  const int tid = threadIdx.x;
  const int col0 = blockIdx.x * 128, row0 = blockIdx.y * 128;
  const int lane = tid & 63, wv = tid >> 6;
  const int wr = (wv & 1) * 64, wc = (wv >> 1) * 64;
  const int fr = lane & 15, quad = lane >> 4;
  const int sr = tid >> 1, skk = (tid & 1) * 16;
  f32x4 acc[4][4] = {};
  for (int k0 = 0; k0 < K; k0 += 32) {
    stage16(&sA[sr][skk], &A[(size_t)(row0 + sr) * lda + k0 + skk]);
    stage16(&sW[sr][skk], &W[(size_t)(col0 + sr) * ldw + k0 + skk]);
    __syncthreads();
    bf16x8 af[4], wf[4];
    #pragma unroll
    for (int mt = 0; mt < 4; ++mt) af[mt] = *(const bf16x8*)&sA[wr + mt*16 + fr][quad*8];
    #pragma unroll
    for (int nt = 0; nt < 4; ++nt) wf[nt] = *(const bf16x8*)&sW[wc + nt*16 + fr][quad*8];
    #pragma unroll
    for (int mt = 0; mt < 4; ++mt)
      #pragma unroll
      for (int nt = 0; nt < 4; ++nt)
        acc[mt][nt] = MFMA_BF16(af[mt], wf[nt], acc[mt][nt], 0, 0, 0);
    __syncthreads();
  }
  #pragma unroll
  for (int nt = 0; nt < 4; ++nt) {
    int col = col0 + wc + nt*16 + fr;
    float bs = bias1 ? bias1[col] : 0.f;
    #pragma unroll
    for (int mt = 0; mt < 4; ++mt)
      #pragma unroll
      for (int r = 0; r < 4; ++r) {
        int row = row0 + wr + mt*16 + quad*4 + r;
        int orow = tmaj ? ((row & 511) * 64 + (row >> 9)) : row;
        out[(size_t)orow * ldo + col] = f2bf(acc[mt][nt][r] + bs);
      }
  }
}

// ---------------------------------------------------------------------------
// Fence-free grid barrier with BOUNDED spins (sticky dead flag on timeout).
// ---------------------------------------------------------------------------
__device__ __forceinline__ void spin_gen(unsigned* gen, unsigned g, unsigned* dead) {
  int n = 0;
  while (__hip_atomic_load(gen, __ATOMIC_RELAXED, __HIP_MEMORY_SCOPE_AGENT) == g) {
    __builtin_amdgcn_s_sleep(4);
    if (++n > 20000) {
      __hip_atomic_store(dead, 1u, __ATOMIC_RELAXED, __HIP_MEMORY_SCOPE_AGENT);
      break;
    }
    if ((n & 1023) == 0 &&
        __hip_atomic_load(dead, __ATOMIC_RELAXED, __HIP_MEMORY_SCOPE_AGENT) != 0u)
      break;
  }
}

__device__ __forceinline__ void grid_sync(unsigned* bar) {
  __syncthreads();
  if (threadIdx.x == 0) {
    unsigned* gen  = bar + 288;
    unsigned* dead = bar + 320;
    if (__hip_atomic_load(dead, __ATOMIC_RELAXED, __HIP_MEMORY_SCOPE_AGENT) == 0u) {
      unsigned g = __hip_atomic_load(gen, __ATOMIC_RELAXED, __HIP_MEMORY_SCOPE_AGENT);
      unsigned grp = blockIdx.x & 7u;
      unsigned old = __hip_atomic_fetch_add(bar + grp * 32, 1u,
                        __ATOMIC_RELAXED, __HIP_MEMORY_SCOPE_AGENT);
      if (old == 31u) {
        unsigned r = __hip_atomic_fetch_add(bar + 256, 1u,
                        __ATOMIC_RELAXED, __HIP_MEMORY_SCOPE_AGENT);
        if (r == 7u) {
          #pragma unroll
          for (int i = 0; i < 8; ++i)
            __hip_atomic_store(bar + i * 32, 0u, __ATOMIC_RELAXED, __HIP_MEMORY_SCOPE_AGENT);
          __hip_atomic_store(bar + 256, 0u, __ATOMIC_RELAXED, __HIP_MEMORY_SCOPE_AGENT);
          __builtin_amdgcn_s_waitcnt(0);     // resets globally ack'd before flip
          __hip_atomic_store(gen, g + 1u, __ATOMIC_RELAXED, __HIP_MEMORY_SCOPE_AGENT);
        } else {
          spin_gen(gen, g, dead);
        }
      } else {
        spin_gen(gen, g, dead);
      }
    }
  }
  __syncthreads();
}

struct LoopArgs {
  const ushort_t *Sproj, *Vproj, *Xproj;            // precomputed bf16
  const ushort_t *WRf, *Whhf, *Wqf, *Wihf;          // frag-packed bf16 weights
  const ushort_t *hsb;                              // bf16 h_s
  const float *bR, *Ww, *bih, *bhh, *hv;            // fp32 inputs
  float *ru, *expb, *s4;                            // cross-block scratch
  uint_t *hrep, *hsrep;                             // h / Hs in MFMA-frag dwords
  unsigned *bar;
  float *out;                                       // (B,T,HI) fp32
};

// frag dword layout for a 64x512 bf16 matrix (h, Hs):
//   element (row r, col c): mt=r>>4, kc=c>>5, quad=(c>>3)&3, e=c&7
//   dword = ((mt*16+kc)*4+quad)*64 + (r&15)*4 + (e>>1); per-mt slice = 16 KB.

// 256 blocks x 512 threads, persistent over T=512 steps, 4 barriers/step.
__global__ __launch_bounds__(512, 2) void loop_kernel(LoopArgs p) {
  const int blk = blockIdx.x, tid = threadIdx.x;
  const int lane = tid & 63, wv = tid >> 6;
  const int fr = lane & 15, quad = lane >> 4;
  // XCD-friendly (b4,q4) for phases B/C: b4's slice lives on xcd = blk&7.
  const int b4 = (blk & 7) * 8 + (blk >> 5);
  const int q4 = (blk >> 3) & 3;

  const bool isGate = (blk < 128);
  const bool isRu   = (blk >= 128) && (blk < 144);
  const int mtG = blk >> 5;                          // gate: batch group 0..3
  const int jt  = (blk & 7) * 4 + ((blk >> 3) & 3);  // gate: j-tile 0..31
  const int g   = wv & 3, kh = wv >> 2;              // gate wave: group, K-half
  const int mtR = (blk - 128) >> 2;                  // ru: batch group
  const int ct  = ((blk - 128) & 3) * 8 + wv;        // ru wave: col tile 0..31

  __shared__ __align__(16) uint_t sH[4096];          // 16 KB staged frag slice
  __shared__ __align__(16) float s_ru[512];
  __shared__ __align__(16) float s_ww[512];
  __shared__ __align__(16) float s_red[512];
  __shared__ __align__(16) float s_acc[8][256];
  __shared__ float s_hsv[128];
  __shared__ float s_alpha[80];
  __shared__ float s_hh[256];
  __shared__ float s_bias[64];

  s_ww[tid] = p.Ww[tid];
  if (isGate && tid < 64) {
    int n = (tid >> 4) * 512 + jt * 16 + (tid & 15);
    s_bias[tid] = p.bih[n] + p.bhh[n];
  }
  float c_reg = 0.f;

  // ---- loop-invariant weight fragments in VGPRs ---------------------------
  // gate: wf2[0..7] = Whh (this wave's K-half), wf2[8..15] = Wq (same half)
  // ru:   wf2[0..15] = WR full K
  bf16x8 wf2[16];
  bf16x8 wfx[16];                                    // gate fallback (in-loop X)
  if (isGate) {
    #pragma unroll
    for (int kc = 0; kc < 8; ++kc) {
      int kcg = kh * 8 + kc;
      wf2[kc]     = *(const bf16x8*)&p.Whhf[((size_t)(jt*4+g)*16 + kcg)*512 + lane*8];
      wf2[8 + kc] = *(const bf16x8*)&p.Wqf [((size_t)(jt*4+g)*16 + kcg)*512 + lane*8];
    }
    if (!p.Xproj) {
      #pragma unroll
      for (int kc = 0; kc < 16; ++kc)
        wfx[kc] = *(const bf16x8*)&p.Wihf[((size_t)(jt*4+g)*32 + kh*16 + kc)*512 + lane*8];
    }
  } else if (isRu) {
    #pragma unroll
    for (int kc = 0; kc < 16; ++kc)
      wf2[kc] = *(const bf16x8*)&p.WRf[((size_t)ct*16 + kc)*512 + lane*8];
  }
  __syncthreads();

  f32x4 accA = {};
  for (int t = 0; t < 512; ++t) {
    // ====== Phase A: hh-MFMA (gate, regs only) + ru-MFMA (ru, write) =======
    if (isGate) {
      f32x4 acc = {};
      if (!p.Xproj) {                                // in-loop X fallback
        int row = mtG * 16 + fr;
        #pragma unroll
        for (int kc = 0; kc < 16; ++kc) {
          bf16x8 af = cvt8(&p.hv[((size_t)row * 512 + t) * 1024 + kh*512 + kc*32 + quad*8]);
          acc = MFMA_BF16(af, wfx[kc], acc, 0, 0, 0);
        }
      }
      if (t) {
        const uint_t* src = p.hrep + mtG * 4096;
        uint_t hst[8];
        #pragma unroll
        for (int i = 0; i < 8; ++i) hst[i] = ldcg_u(src + i * 512 + tid);
        #pragma unroll
        for (int i = 0; i < 8; ++i) sH[i * 512 + tid] = hst[i];
        __syncthreads();
        #pragma unroll
        for (int kc = 0; kc < 8; ++kc) {
          int kcg = kh * 8 + kc;
          bf16x8 af = *(const bf16x8*)&sH[kcg * 256 + quad * 64 + fr * 4];
          acc = MFMA_BF16(af, wf2[kc], acc, 0, 0, 0);
        }
      }
      accA = acc;                                    // lives until Phase D
    } else if (isRu) {
      f32x4 acc = {};
      if (t) {
        const uint_t* src = p.hrep + mtR * 4096;
        uint_t hst[8];
        #pragma unroll
        for (int i = 0; i < 8; ++i) hst[i] = ldcg_u(src + i * 512 + tid);
        #pragma unroll
        for (int i = 0; i < 8; ++i) sH[i * 512 + tid] = hst[i];
        __syncthreads();
        #pragma unroll
        for (int kc = 0; kc < 16; ++kc) {
          bf16x8 af = *(const bf16x8*)&sH[kc * 256 + quad * 64 + fr * 4];
          acc = MFMA_BF16(af, wf2[kc], acc, 0, 0, 0);
        }
      }
      #pragma unroll
      for (int r = 0; r < 4; ++r) {
        int row = mtR * 16 + quad * 4 + r, col = ct * 16 + fr;
        float v = acc[r] + p.bR[col] + bf2f(p.Vproj[(size_t)t * 32768 + row * 512 + col]);
        stcg_f(&p.ru[row * 512 + col], v);
      }
    }
    grid_sync(p.bar);

    // ====== Phase B: attention beta -> exp + partial denominators ==========
    s_ru[tid] = ldcg_f(&p.ru[b4 * 512 + tid]);
    __syncthreads();
    #pragma unroll
    for (int rr = 0; rr < 3; ++rr) {
      int nl = wv + 8 * rr;
      if (nl < 20) {
        int n = q4 * 20 + nl;
        uint4 sv = *(const uint4*)&p.Sproj[((size_t)(b4 * 80 + n)) * 512 + lane * 8];
        float4 r0 = *(const float4*)&s_ru[lane * 8];
        float4 r1 = *(const float4*)&s_ru[lane * 8 + 4];
        float4 w0 = *(const float4*)&s_ww[lane * 8];
        float4 w1 = *(const float4*)&s_ww[lane * 8 + 4];
        float a = 0.f;
        a += tanh_(bf2f((ushort_t)(sv.x & 0xFFFF)) + r0.x) * w0.x;
        a += tanh_(bf2f((ushort_t)(sv.x >> 16))    + r0.y) * w0.y;
        a += tanh_(bf2f((ushort_t)(sv.y & 0xFFFF)) + r0.z) * w0.z;
        a += tanh_(bf2f((ushort_t)(sv.y >> 16))    + r0.w) * w0.w;
        a += tanh_(bf2f((ushort_t)(sv.z & 0xFFFF)) + r1.x) * w1.x;
        a += tanh_(bf2f((ushort_t)(sv.z >> 16))    + r1.y) * w1.y;
        a += tanh_(bf2f((ushort_t)(sv.w & 0xFFFF)) + r1.z) * w1.z;
        a += tanh_(bf2f((ushort_t)(sv.w >> 16))    + r1.w) * w1.w;
        #pragma unroll
        for (int off = 32; off > 0; off >>= 1) a += __shfl_xor(a, off, 64);
        if (lane == 0) {
          // |beta| <= sum|W_w| ~ 8 -> exp safe without max-subtraction
          float e = __expf(a);
          stcg_f(&p.expb[b4 * 80 + n], e);
          __hip_atomic_fetch_add(&p.s4[(t & 1) * 320 + (b4 & 3) * 80 + n], e,
                                 __ATOMIC_RELAXED, __HIP_MEMORY_SCOPE_AGENT);
        }
      }
    }
    grid_sync(p.bar);

    // ====== Phase C: alpha + Hs slice -> hsrep (frag layout) ===============
    if (tid < 80) {
      const float* sc = p.s4 + (t & 1) * 320;
      float s = ldcg_f(sc + tid) + ldcg_f(sc + 80 + tid) +
                ldcg_f(sc + 160 + tid) + ldcg_f(sc + 240 + tid);
      float e = ldcg_f(&p.expb[b4 * 80 + tid]);
      s_alpha[tid] = e * __builtin_amdgcn_rcpf(s);
    }
    if (blk == 0 && tid < 320)                       // zero next-parity denoms
      stcg_f(&p.s4[((t + 1) & 1) * 320 + tid], 0.f);
    __syncthreads();
    {
      int nq = tid >> 7, jl = tid & 127;             // 4-way n-split per j
      const ushort_t* hp = p.hsb + (size_t)b4 * 40960 + q4 * 128 + jl;
      float part = 0.f;
      #pragma unroll 5
      for (int n0 = 0; n0 < 20; ++n0) {
        int n = nq * 20 + n0;
        part += s_alpha[n] * bf2f(hp[(size_t)n * 512]);
      }
      s_red[tid] = part;
    }
    __syncthreads();
    if (tid < 128)
      s_hsv[tid] = s_red[tid] + s_red[128 + tid] + s_red[256 + tid] + s_red[384 + tid];
    __syncthreads();
    if (tid < 64) {
      int c = q4 * 128 + tid * 2;
      int kc = c >> 5, qd = (c >> 3) & 3, e2 = (c & 7) >> 1;
      int dw = (((b4 >> 4) * 16 + kc) * 4 + qd) * 64 + (b4 & 15) * 4 + e2;
      stcg_u(&p.hsrep[dw], pk(s_hsv[tid * 2], s_hsv[tid * 2 + 1]));
    }
    grid_sync(p.bar);

    // ====== Phase D: Hs-MFMA + gates assembly + pointwise + h (gate only) ==
    if (isGate) {
      const uint_t* src = p.hsrep + mtG * 4096;
      uint_t hst[8];
      #pragma unroll
      for (int i = 0; i < 8; ++i) hst[i] = ldcg_u(src + i * 512 + tid);
      #pragma unroll
      for (int i = 0; i < 8; ++i) sH[i * 512 + tid] = hst[i];
      __syncthreads();
      f32x4 acc = accA;
      #pragma unroll
      for (int kc = 0; kc < 8; ++kc) {
        int kcg = kh * 8 + kc;
        bf16x8 af = *(const bf16x8*)&sH[kcg * 256 + quad * 64 + fr * 4];
        acc = MFMA_BF16(af, wf2[8 + kc], acc, 0, 0, 0);
      }
      #pragma unroll
      for (int r = 0; r < 4; ++r) s_acc[wv][(quad * 4 + r) * 16 + fr] = acc[r];
      __syncthreads();
      if (tid < 256) {
        int b = tid >> 4, jj = tid & 15, bi = tid;
        float g0 = s_acc[0][bi] + s_acc[4][bi] + s_bias[jj];
        float g1 = s_acc[1][bi] + s_acc[5][bi] + s_bias[16 + jj];
        float g2 = s_acc[2][bi] + s_acc[6][bi] + s_bias[32 + jj];
        float g3 = s_acc[3][bi] + s_acc[7][bi] + s_bias[48 + jj];
        if (p.Xproj) {
          const ushort_t* xp = &p.Xproj[(size_t)t * 131072 +
                                        (size_t)(mtG * 16 + b) * 2048 + jt * 16 + jj];
          g0 += bf2f(xp[0]);    g1 += bf2f(xp[512]);
          g2 += bf2f(xp[1024]); g3 += bf2f(xp[1536]);
        }
        float ig = sigm_(g0), fg = sigm_(g1), gv = tanh_(g2), og = sigm_(g3);
        float cn = fg * c_reg + ig * gv;
        c_reg = cn;
        float hn = og * tanh_(cn);
        s_hh[bi] = hn;
        p.out[((size_t)(mtG * 16 + b) * 512 + t) * 512 + jt * 16 + jj] = hn;
      }
      __syncthreads();
      if (tid < 128) {                               // pack h -> frag layout
        int b = tid >> 3, jp = tid & 7;
        int c = jt * 16 + jp * 2;
        int kc = c >> 5, qd = (c >> 3) & 3, e2 = (c & 7) >> 1;
        int dw = ((mtG * 16 + kc) * 4 + qd) * 64 + b * 4 + e2;
        stcg_u(&p.hrep[dw], pk(s_hh[b * 16 + jp * 2], s_hh[b * 16 + jp * 2 + 1]));
      }
    }
    grid_sync(p.bar);
  }
}

// ===========================================================================
extern "C" void kernel_launch(void* const* d_in, const int* in_sizes, int n_in,
                              void* d_out, int out_size, void* d_ws, size_t ws_size,
                              hipStream_t stream) {
  (void)in_sizes; (void)n_in; (void)out_size;
  const float* hv   = (const float*)d_in[0];
  const float* hs   = (const float*)d_in[1];
  const float* W_S  = (const float*)d_in[2];
  const float* b_S  = (const float*)d_in[3];
  const float* W_V  = (const float*)d_in[4];
  const float* b_V  = (const float*)d_in[5];
  const float* W_R  = (const float*)d_in[6];
  const float* b_R  = (const float*)d_in[7];
  const float* W_w  = (const float*)d_in[8];
  /* d_in[9] = b_w: dropped (softmax shift-invariance) */
  const float* W_ih = (const float*)d_in[10];
  const float* b_ih = (const float*)d_in[11];
  const float* W_hh = (const float*)d_in[12];
  const float* b_hh = (const float*)d_in[13];

  char* ws = (char*)d_ws;
  unsigned long long off = 0;
  auto alloc = [&](unsigned long long bytes) {
    unsigned long long pp = off; off += (bytes + 255ull) & ~255ull; return pp;
  };
  ushort_t* Sproj = (ushort_t*)(ws + alloc(5120ull * 512 * 2));
  ushort_t* Vproj = (ushort_t*)(ws + alloc(512ull * 64 * 512 * 2));   // time-major
  ushort_t* hsb   = (ushort_t*)(ws + alloc(64ull * 80 * 512 * 2));
  ushort_t* WRf   = (ushort_t*)(ws + alloc(512ull * 512 * 2));
  ushort_t* Whhf  = (ushort_t*)(ws + alloc(2048ull * 512 * 2));
  ushort_t* Wqf   = (ushort_t*)(ws + alloc(2048ull * 512 * 2));
  float*    ru    = (float*)(ws + alloc(64ull * 512 * 4));
  float*    expb  = (float*)(ws + alloc(64ull * 80 * 4));
  unsigned long long zoff = off;
  uint_t*   hrep  = (uint_t*)(ws + alloc(16384ull * 4));
  uint_t*   hsrep = (uint_t*)(ws + alloc(16384ull * 4));
  float*    s4    = (float*)(ws + alloc(2ull * 4 * 80 * 4));
  unsigned* bar   = (unsigned*)(ws + alloc(2048));
  unsigned long long zsize = off - zoff;
  unsigned long long tail = off;                    // Xproj or Wihf goes here
  bool precX = ws_size >= tail + 512ull * 64 * 2048 * 2 + 4096;
  ushort_t* Xproj = precX ? (ushort_t*)(ws + tail) : nullptr;
  ushort_t* Wihf  = precX ? nullptr : (ushort_t*)(ws + tail);

  cvt_kernel<<<2560, 256, 0, stream>>>(hs, hsb, 64 * 80 * 512 / 4);
  pack_frag_kernel<<<128, 256, 0, stream>>>(W_R,  512,  0,    WRf,  0, 4);
  pack_frag_kernel<<<512, 256, 0, stream>>>(W_hh, 512,  0,    Whhf, 1, 4);
  pack_frag_kernel<<<512, 256, 0, stream>>>(W_ih, 1536, 1024, Wqf,  1, 4);
  if (!precX)
    pack_frag_kernel<<<1024, 256, 0, stream>>>(W_ih, 1536, 0, Wihf, 1, 5);

  // S_proj = h_s.W_S^T + b_S            (5120 x 512, K=512), row-major
  gemm_bt<<<dim3(4, 40), 256, 0, stream>>>(hs, 512, W_S, 512, b_S, Sproj, 512, 512, 0);
  // V_proj = h_v.W_V^T + b_V            (32768 x 512, K=1024), time-major
  gemm_bt<<<dim3(4, 256), 256, 0, stream>>>(hv, 1024, W_V, 1024, b_V, Vproj, 512, 1024, 1);
  // Xproj = h_v.(W_ih[:, :1024])^T      (32768 x 2048, K=1024), time-major
  if (precX)
    gemm_bt<<<dim3(16, 256), 256, 0, stream>>>(hv, 1024, W_ih, 1536, nullptr, Xproj, 2048, 1024, 1);

  hipMemsetAsync(ws + zoff, 0, (size_t)zsize, stream);   // hrep/hsrep/s4/bar = 0

  LoopArgs la;
  la.Sproj = Sproj; la.Vproj = Vproj; la.Xproj = Xproj;
  la.WRf = WRf; la.Whhf = Whhf; la.Wqf = Wqf; la.Wihf = Wihf;
  la.hsb = hsb;
  la.bR = b_R; la.Ww = W_w; la.bih = b_ih; la.bhh = b_hh; la.hv = hv;
  la.ru = ru; la.expb = expb; la.s4 = s4;
  la.hrep = hrep; la.hsrep = hsrep; la.bar = bar; la.out = (float*)d_out;
  loop_kernel<<<256, 512, 0, stream>>>(la);
}

// Round 5
// 11137.997 us; speedup vs baseline: 2.1655x; 1.1142x over previous
//
#include <hip/hip_runtime.h>

// ============================================================================
// Interactor (attention-gated LSTM), MI355X gfx950. FP32 I/O; bf16 MFMA inside.
// Round 8: localized sync graph. Group G=blk>>6 (64 blocks) owns batch rows
// [G*16,+16) for gates (mtG=G), ru (mtR=G) and beta/C (b4 in G's range), so:
//   - ru ready:   P2P monotonic counter rcnt[G] (4 producers, thr=4(t+1))
//   - C->D, D->A: 64-block GROUP barriers (h / Hs exchanges are in-group)
//   - B->C:       the one real GLOBAL barrier (batch softmax denominator)
// s4 partials per (G,n) with 3-parity + zero-at-C (global-bar-ordered);
// expb transposed [n*64+b4], 2-parity. Xproj prefetched in A, used in D.
// Bounded spins + sticky dead flag everywhere (deadlock => finishes wrong,
// never hangs the container).
// ============================================================================

typedef unsigned short ushort_t;
typedef unsigned int uint_t;
typedef __attribute__((ext_vector_type(8))) short bf16x8;   // 8 x bf16
typedef __attribute__((ext_vector_type(4))) float f32x4;

#define MFMA_BF16 __builtin_amdgcn_mfma_f32_16x16x32_bf16

__device__ __forceinline__ float bf2f(ushort_t u) {
  return __builtin_bit_cast(float, (uint_t)u << 16);
}
__device__ __forceinline__ ushort_t f2bf(float f) {   // round-to-nearest-even
  uint_t u = __builtin_bit_cast(uint_t, f);
  u += 0x7FFFu + ((u >> 16) & 1u);
  return (ushort_t)(u >> 16);
}
__device__ __forceinline__ uint_t pk(float lo, float hi) {
  return (uint_t)f2bf(lo) | ((uint_t)f2bf(hi) << 16);
}
__device__ __forceinline__ void stage16(ushort_t* dst, const float* src) {
  float4 a = *(const float4*)src,     b = *(const float4*)(src + 4);
  float4 c = *(const float4*)(src + 8), d = *(const float4*)(src + 12);
  uint4 lo = { pk(a.x,a.y), pk(a.z,a.w), pk(b.x,b.y), pk(b.z,b.w) };
  uint4 hi = { pk(c.x,c.y), pk(c.z,c.w), pk(d.x,d.y), pk(d.z,d.w) };
  *(uint4*)dst = lo; *(uint4*)(dst + 8) = hi;
}
__device__ __forceinline__ bf16x8 cvt8(const float* src) {
  float4 a = *(const float4*)src, b = *(const float4*)(src + 4);
  uint4 u = { pk(a.x,a.y), pk(a.z,a.w), pk(b.x,b.y), pk(b.z,b.w) };
  return __builtin_bit_cast(bf16x8, u);
}
__device__ __forceinline__ float tanh_(float x) {
  float e = __expf(2.f * x);
  return 1.f - 2.f * __builtin_amdgcn_rcpf(e + 1.f);
}
__device__ __forceinline__ float sigm_(float x) {
  return __builtin_amdgcn_rcpf(1.f + __expf(-x));
}

// -------- device-coherent (MALL) accessors ---------------------------------
__device__ __forceinline__ float ldcg_f(const float* p) {
  return __hip_atomic_load(p, __ATOMIC_RELAXED, __HIP_MEMORY_SCOPE_AGENT);
}
__device__ __forceinline__ void stcg_f(float* p, float v) {
  __hip_atomic_store(p, v, __ATOMIC_RELAXED, __HIP_MEMORY_SCOPE_AGENT);
}
__device__ __forceinline__ uint_t ldcg_u(const uint_t* p) {
  return __hip_atomic_load(p, __ATOMIC_RELAXED, __HIP_MEMORY_SCOPE_AGENT);
}
__device__ __forceinline__ void stcg_u(uint_t* p, uint_t v) {
  __hip_atomic_store(p, v, __ATOMIC_RELAXED, __HIP_MEMORY_SCOPE_AGENT);
}

// fp32 -> bf16 elementwise (n4 = count of float4 groups)
__global__ __launch_bounds__(256) void cvt_kernel(
    const float* __restrict__ in, ushort_t* __restrict__ out, int n4) {
  int i = blockIdx.x * blockDim.x + threadIdx.x;
  if (i < n4) {
    float4 v = ((const float4*)in)[i];
    uint2 r = { pk(v.x, v.y), pk(v.z, v.w) };
    ((uint2*)out)[i] = r;
  }
}

// ---------------------------------------------------------------------------
// Pack weight rows into per-tile MFMA B-fragment order:
//   out[(tile*KCT + kc)*512 + lane*8 + e] = src[row*ld + coff + kc*32 + (lane>>4)*8 + e]
//   row = mode ? (tile&3)*512 + (tile>>2)*16 + (lane&15) : tile*16 + (lane&15)
// lkc = log2(KCT). One thread packs 8 elements.
// ---------------------------------------------------------------------------
__global__ __launch_bounds__(256) void pack_frag_kernel(
    const float* __restrict__ src, int ld, int coff,
    ushort_t* __restrict__ out, int mode, int lkc) {
  size_t o = ((size_t)blockIdx.x * 256 + threadIdx.x) * 8;
  int lane = (int)((o >> 3) & 63);
  int kc   = (int)((o >> 9) & ((1u << lkc) - 1u));
  int tile = (int)(o >> (9 + lkc));
  int row  = mode ? ((tile & 3) * 512 + (tile >> 2) * 16 + (lane & 15))
                  : (tile * 16 + (lane & 15));
  int col  = kc * 32 + (lane >> 4) * 8;
  const float* s = &src[(size_t)row * ld + coff + col];
  float4 a = *(const float4*)s, b = *(const float4*)(s + 4);
  uint4 u = { pk(a.x,a.y), pk(a.z,a.w), pk(b.x,b.y), pk(b.z,b.w) };
  *(uint4*)&out[o] = u;
}

// ---------------------------------------------------------------------------
// C = A*W^T (+bias), A:[MxK] fp32 (lda), W:[NxK] fp32 (ldw), out bf16 [..xldo].
// tmaj: output row remap row -> (row&511)*64 + (row>>9)  (time-major (t,b)).
// ---------------------------------------------------------------------------
__global__ __launch_bounds__(256) void gemm_bt(
    const float* __restrict__ A, int lda,
    const float* __restrict__ W, int ldw,
    const float* __restrict__ bias1,
    ushort_t* __restrict__ out, int ldo, int K, int tmaj)
{
  __shared__ __align__(16) ushort_t sA[128][32];
  __shared__ __align__(16) ushort_t sW[128][32];
  const int tid = threadIdx.x;
  const int col0 = blockIdx.x * 128, row0 = blockIdx.y * 128;
  const int lane = tid & 63, wv = tid >> 6;
  const int wr = (wv & 1) * 64, wc = (wv >> 1) * 64;
  const int fr = lane & 15, quad = lane >> 4;
  const int sr = tid >> 1, skk = (tid & 1) * 16;
  f32x4 acc[4][4] = {};
  for (int k0 = 0; k0 < K; k0 += 32) {
    stage16(&sA[sr][skk], &A[(size_t)(row0 + sr) * lda + k0 + skk]);
    stage16(&sW[sr][skk], &W[(size_t)(col0 + sr) * ldw + k0 + skk]);
    __syncthreads();
    bf16x8 af[4], wf[4];
    #pragma unroll
    for (int mt = 0; mt < 4; ++mt) af[mt] = *(const bf16x8*)&sA[wr + mt*16 + fr][quad*8];
    #pragma unroll
    for (int nt = 0; nt < 4; ++nt) wf[nt] = *(const bf16x8*)&sW[wc + nt*16 + fr][quad*8];
    #pragma unroll
    for (int mt = 0; mt < 4; ++mt)
      #pragma unroll
      for (int nt = 0; nt < 4; ++nt)
        acc[mt][nt] = MFMA_BF16(af[mt], wf[nt], acc[mt][nt], 0, 0, 0);
    __syncthreads();
  }
  #pragma unroll
  for (int nt = 0; nt < 4; ++nt) {
    int col = col0 + wc + nt*16 + fr;
    float bs = bias1 ? bias1[col] : 0.f;
    #pragma unroll
    for (int mt = 0; mt < 4; ++mt)
      #pragma unroll
      for (int r = 0; r < 4; ++r) {
        int row = row0 + wr + mt*16 + quad*4 + r;
        int orow = tmaj ? ((row & 511) * 64 + (row >> 9)) : row;
        out[(size_t)orow * ldo + col] = f2bf(acc[mt][nt][r] + bs);
      }
  }
}

// ---------------------------------------------------------------------------
// Parametric fence-free barrier (8 roots). base layout (dwords):
//   [sub*32] sub counters (8), [256] root, [288] gen. Bounded spins; shared
//   sticky dead flag. Global: sub=blk&7, sub_last=31. Group: sub=w6&7, last=7.
// ---------------------------------------------------------------------------
__device__ __forceinline__ void spin_gen(unsigned* gen, unsigned g, unsigned* dead) {
  int n = 0;
  while (__hip_atomic_load(gen, __ATOMIC_RELAXED, __HIP_MEMORY_SCOPE_AGENT) == g) {
    __builtin_amdgcn_s_sleep(4);
    if (++n > 20000) {
      __hip_atomic_store(dead, 1u, __ATOMIC_RELAXED, __HIP_MEMORY_SCOPE_AGENT);
      break;
    }
    if ((n & 1023) == 0 &&
        __hip_atomic_load(dead, __ATOMIC_RELAXED, __HIP_MEMORY_SCOPE_AGENT) != 0u)
      break;
  }
}

__device__ __forceinline__ void sync_bar(unsigned* base, unsigned sub,
                                         unsigned sub_last, unsigned* dead) {
  __syncthreads();
  if (threadIdx.x == 0) {
    unsigned* gen = base + 288;
    if (__hip_atomic_load(dead, __ATOMIC_RELAXED, __HIP_MEMORY_SCOPE_AGENT) == 0u) {
      unsigned g = __hip_atomic_load(gen, __ATOMIC_RELAXED, __HIP_MEMORY_SCOPE_AGENT);
      unsigned old = __hip_atomic_fetch_add(base + sub * 32, 1u,
                        __ATOMIC_RELAXED, __HIP_MEMORY_SCOPE_AGENT);
      if (old == sub_last) {
        unsigned r = __hip_atomic_fetch_add(base + 256, 1u,
                        __ATOMIC_RELAXED, __HIP_MEMORY_SCOPE_AGENT);
        if (r == 7u) {
          #pragma unroll
          for (int i = 0; i < 8; ++i)
            __hip_atomic_store(base + i * 32, 0u, __ATOMIC_RELAXED, __HIP_MEMORY_SCOPE_AGENT);
          __hip_atomic_store(base + 256, 0u, __ATOMIC_RELAXED, __HIP_MEMORY_SCOPE_AGENT);
          __builtin_amdgcn_s_waitcnt(0);     // resets globally ack'd before flip
          __hip_atomic_store(gen, g + 1u, __ATOMIC_RELAXED, __HIP_MEMORY_SCOPE_AGENT);
        } else {
          spin_gen(gen, g, dead);
        }
      } else {
        spin_gen(gen, g, dead);
      }
    }
  }
  __syncthreads();
}

struct LoopArgs {
  const ushort_t *Sproj, *Vproj, *Xproj;            // precomputed bf16
  const ushort_t *WRf, *Whhf, *Wqf, *Wihf;          // frag-packed bf16 weights
  const ushort_t *hsb;                              // bf16 h_s
  const float *bR, *Ww, *bih, *bhh, *hv;            // fp32 inputs
  float *ru, *expb, *s4;                            // cross-block scratch
  uint_t *hrep, *hsrep;                             // h / Hs in MFMA-frag dwords
  unsigned *bar;
  float *out;                                       // (B,T,HI) fp32
};

// frag dword layout for a 64x512 bf16 matrix (h, Hs):
//   element (row r, col c): mt=r>>4, kc=c>>5, quad=(c>>3)&3, e=c&7
//   dword = ((mt*16+kc)*4+quad)*64 + (r&15)*4 + (e>>1); per-mt slice = 16 KB.
// bar layout (dwords): [0..288] global bar, [320] dead, [384+G] rcnt,
//   [512+G*512 ...] group-G bar (same internal layout).

// 256 blocks x 512 threads, persistent over T=512 steps.
// Per step: P2P(ru) + 1 global bar + 2 group bars.
__global__ __launch_bounds__(512, 2) void loop_kernel(LoopArgs p) {
  const int blk = blockIdx.x, tid = threadIdx.x;
  const int lane = tid & 63, wv = tid >> 6;
  const int fr = lane & 15, quad = lane >> 4;
  const int G = blk >> 6, w6 = blk & 63;
  const int b4 = G * 16 + (w6 & 15), q = w6 >> 4;   // beta/C role
  const bool isGate = (w6 < 32);
  const bool isRu   = (w6 >= 32) && (w6 < 36);
  const int jt = w6 & 31;                           // gate j-tile
  const int g = wv & 3, kh = wv >> 2;               // gate wave roles
  const int ct = ((w6 - 32) & 3) * 8 + wv;          // ru wave col-tile 0..31

  unsigned* dead = p.bar + 320;
  unsigned* rcnt = p.bar + 384 + G;
  unsigned* gbar = p.bar + 512 + G * 512;

  __shared__ __align__(16) uint_t sH[4096];         // 16 KB staged frag slice
  __shared__ __align__(16) float s_ru[512];
  __shared__ __align__(16) float s_ww[512];
  __shared__ __align__(16) float s_red[512];
  __shared__ __align__(16) float s_acc[8][256];
  __shared__ float s_hsv[128];
  __shared__ float s_alpha[80];
  __shared__ float s_hh[256];
  __shared__ float s_bias[64];

  s_ww[tid] = p.Ww[tid];
  if (isGate && tid < 64) {
    int n = (tid >> 4) * 512 + jt * 16 + (tid & 15);
    s_bias[tid] = p.bih[n] + p.bhh[n];
  }
  float c_reg = 0.f;

  // ---- loop-invariant weight fragments in VGPRs ---------------------------
  bf16x8 wf2[16];
  bf16x8 wfx[16];                                   // gate fallback (in-loop X)
  if (isGate) {
    #pragma unroll
    for (int kc = 0; kc < 8; ++kc) {
      int kcg = kh * 8 + kc;
      wf2[kc]     = *(const bf16x8*)&p.Whhf[((size_t)(jt*4+g)*16 + kcg)*512 + lane*8];
      wf2[8 + kc] = *(const bf16x8*)&p.Wqf [((size_t)(jt*4+g)*16 + kcg)*512 + lane*8];
    }
    if (!p.Xproj) {
      #pragma unroll
      for (int kc = 0; kc < 16; ++kc)
        wfx[kc] = *(const bf16x8*)&p.Wihf[((size_t)(jt*4+g)*32 + kh*16 + kc)*512 + lane*8];
    }
  } else if (isRu) {
    #pragma unroll
    for (int kc = 0; kc < 16; ++kc)
      wf2[kc] = *(const bf16x8*)&p.WRf[((size_t)ct*16 + kc)*512 + lane*8];
  }
  __syncthreads();

  f32x4 accA = {};
  for (int t = 0; t < 512; ++t) {
    float x0 = 0.f, x1 = 0.f, x2 = 0.f, x3 = 0.f;   // Xproj prefetch regs
    // ====== Phase A: hh-MFMA (gate) / ru-MFMA + publish (ru) ===============
    if (isGate) {
      f32x4 acc = {};
      if (!p.Xproj) {                               // in-loop X fallback
        int row = G * 16 + fr;
        #pragma unroll
        for (int kc = 0; kc < 16; ++kc) {
          bf16x8 af = cvt8(&p.hv[((size_t)row * 512 + t) * 1024 + kh*512 + kc*32 + quad*8]);
          acc = MFMA_BF16(af, wfx[kc], acc, 0, 0, 0);
        }
      }
      if (t) {
        const uint_t* src = p.hrep + G * 4096;
        uint_t hst[8];
        #pragma unroll
        for (int i = 0; i < 8; ++i) hst[i] = ldcg_u(src + i * 512 + tid);
        #pragma unroll
        for (int i = 0; i < 8; ++i) sH[i * 512 + tid] = hst[i];
        __syncthreads();
        #pragma unroll
        for (int kc = 0; kc < 8; ++kc) {
          int kcg = kh * 8 + kc;
          bf16x8 af = *(const bf16x8*)&sH[kcg * 256 + quad * 64 + fr * 4];
          acc = MFMA_BF16(af, wf2[kc], acc, 0, 0, 0);
        }
      }
      accA = acc;                                   // lives until Phase D
      if (p.Xproj && tid < 256) {                   // prefetch X for Phase D
        const ushort_t* xp = &p.Xproj[(size_t)t * 131072 +
                                      (size_t)(G * 16 + (tid >> 4)) * 2048 + jt * 16 + (tid & 15)];
        x0 = bf2f(xp[0]);    x1 = bf2f(xp[512]);
        x2 = bf2f(xp[1024]); x3 = bf2f(xp[1536]);
      }
    } else if (isRu) {
      f32x4 acc = {};
      if (t) {
        const uint_t* src = p.hrep + G * 4096;
        uint_t hst[8];
        #pragma unroll
        for (int i = 0; i < 8; ++i) hst[i] = ldcg_u(src + i * 512 + tid);
        #pragma unroll
        for (int i = 0; i < 8; ++i) sH[i * 512 + tid] = hst[i];
        __syncthreads();
        #pragma unroll
        for (int kc = 0; kc < 16; ++kc) {
          bf16x8 af = *(const bf16x8*)&sH[kc * 256 + quad * 64 + fr * 4];
          acc = MFMA_BF16(af, wf2[kc], acc, 0, 0, 0);
        }
      }
      #pragma unroll
      for (int r = 0; r < 4; ++r) {
        int row = G * 16 + quad * 4 + r, col = ct * 16 + fr;
        float v = acc[r] + p.bR[col] + bf2f(p.Vproj[(size_t)t * 32768 + row * 512 + col]);
        stcg_f(&p.ru[row * 512 + col], v);
      }
      __syncthreads();                              // drain ru stores (vmcnt)
      if (tid == 0)
        __hip_atomic_fetch_add(rcnt, 1u, __ATOMIC_RELAXED, __HIP_MEMORY_SCOPE_AGENT);
    }

    // ====== Phase B: wait ru (P2P), beta -> exp + s4 partial ===============
    if (tid == 0) {
      unsigned thr = 4u * (unsigned)(t + 1);
      int n = 0;
      while (ldcg_u(rcnt) < thr) {
        __builtin_amdgcn_s_sleep(4);
        if (++n > 20000) {
          stcg_u(dead, 1u);
          break;
        }
        if ((n & 1023) == 0 && ldcg_u(dead) != 0u) break;
      }
    }
    __syncthreads();
    s_ru[tid] = ldcg_f(&p.ru[b4 * 512 + tid]);
    __syncthreads();
    #pragma unroll
    for (int rr = 0; rr < 3; ++rr) {
      int nl = wv + 8 * rr;
      if (nl < 20) {
        int n = q * 20 + nl;
        uint4 sv = *(const uint4*)&p.Sproj[((size_t)(b4 * 80 + n)) * 512 + lane * 8];
        float4 r0 = *(const float4*)&s_ru[lane * 8];
        float4 r1 = *(const float4*)&s_ru[lane * 8 + 4];
        float4 w0 = *(const float4*)&s_ww[lane * 8];
        float4 w1 = *(const float4*)&s_ww[lane * 8 + 4];
        float a = 0.f;
        a += tanh_(bf2f((ushort_t)(sv.x & 0xFFFF)) + r0.x) * w0.x;
        a += tanh_(bf2f((ushort_t)(sv.x >> 16))    + r0.y) * w0.y;
        a += tanh_(bf2f((ushort_t)(sv.y & 0xFFFF)) + r0.z) * w0.z;
        a += tanh_(bf2f((ushort_t)(sv.y >> 16))    + r0.w) * w0.w;
        a += tanh_(bf2f((ushort_t)(sv.z & 0xFFFF)) + r1.x) * w1.x;
        a += tanh_(bf2f((ushort_t)(sv.z >> 16))    + r1.y) * w1.y;
        a += tanh_(bf2f((ushort_t)(sv.w & 0xFFFF)) + r1.z) * w1.z;
        a += tanh_(bf2f((ushort_t)(sv.w >> 16))    + r1.w) * w1.w;
        #pragma unroll
        for (int off = 32; off > 0; off >>= 1) a += __shfl_xor(a, off, 64);
        if (lane == 0) {
          // |beta| <= sum|W_w| ~ 8 -> exp safe without max-subtraction
          float e = __expf(a);
          stcg_f(&p.expb[(t & 1) * 5120 + n * 64 + b4], e);
          __hip_atomic_fetch_add(&p.s4[(t % 3) * 320 + G * 80 + n], e,
                                 __ATOMIC_RELAXED, __HIP_MEMORY_SCOPE_AGENT);
        }
      }
    }
    sync_bar(p.bar, (unsigned)(blk & 7), 31u, dead);      // GLOBAL

    // ====== Phase C: alpha + Hs slice -> hsrep (frag layout) ===============
    if (tid < 80) {
      const float* sc = p.s4 + (t % 3) * 320;
      float s = ldcg_f(sc + tid) + ldcg_f(sc + 80 + tid) +
                ldcg_f(sc + 160 + tid) + ldcg_f(sc + 240 + tid);
      float num = ldcg_f(&p.expb[(t & 1) * 5120 + tid * 64 + b4]);
      s_alpha[tid] = num * __builtin_amdgcn_rcpf(s);
    }
    if (blk == 0 && tid < 320)                      // zero parity t+2 (3-cycle)
      stcg_f(&p.s4[((t + 2) % 3) * 320 + tid], 0.f);
    __syncthreads();
    {
      int nq = tid >> 7, jl = tid & 127;            // 4-way n-split per j
      const ushort_t* hp = p.hsb + (size_t)b4 * 40960 + q * 128 + jl;
      float part = 0.f;
      #pragma unroll 5
      for (int n0 = 0; n0 < 20; ++n0) {
        int n = nq * 20 + n0;
        part += s_alpha[n] * bf2f(hp[(size_t)n * 512]);
      }
      s_red[tid] = part;
    }
    __syncthreads();
    if (tid < 128)
      s_hsv[tid] = s_red[tid] + s_red[128 + tid] + s_red[256 + tid] + s_red[384 + tid];
    __syncthreads();
    if (tid < 64) {
      int c = q * 128 + tid * 2;
      int kc = c >> 5, qd = (c >> 3) & 3, e2 = (c & 7) >> 1;
      int dw = ((G * 16 + kc) * 4 + qd) * 64 + (b4 & 15) * 4 + e2;
      stcg_u(&p.hsrep[dw], pk(s_hsv[tid * 2], s_hsv[tid * 2 + 1]));
    }
    sync_bar(gbar, (unsigned)(w6 & 7), 7u, dead);         // GROUP (C -> D)

    // ====== Phase D: Hs-MFMA + gates + pointwise + h (gate only) ===========
    if (isGate) {
      const uint_t* src = p.hsrep + G * 4096;
      uint_t hst[8];
      #pragma unroll
      for (int i = 0; i < 8; ++i) hst[i] = ldcg_u(src + i * 512 + tid);
      #pragma unroll
      for (int i = 0; i < 8; ++i) sH[i * 512 + tid] = hst[i];
      __syncthreads();
      f32x4 acc = accA;
      #pragma unroll
      for (int kc = 0; kc < 8; ++kc) {
        int kcg = kh * 8 + kc;
        bf16x8 af = *(const bf16x8*)&sH[kcg * 256 + quad * 64 + fr * 4];
        acc = MFMA_BF16(af, wf2[8 + kc], acc, 0, 0, 0);
      }
      #pragma unroll
      for (int r = 0; r < 4; ++r) s_acc[wv][(quad * 4 + r) * 16 + fr] = acc[r];
      __syncthreads();
      if (tid < 256) {
        int b = tid >> 4, jj = tid & 15, bi = tid;
        float g0 = s_acc[0][bi] + s_acc[4][bi] + s_bias[jj];
        float g1 = s_acc[1][bi] + s_acc[5][bi] + s_bias[16 + jj];
        float g2 = s_acc[2][bi] + s_acc[6][bi] + s_bias[32 + jj];
        float g3 = s_acc[3][bi] + s_acc[7][bi] + s_bias[48 + jj];
        if (p.Xproj) { g0 += x0; g1 += x1; g2 += x2; g3 += x3; }
        float ig = sigm_(g0), fg = sigm_(g1), gv = tanh_(g2), og = sigm_(g3);
        float cn = fg * c_reg + ig * gv;
        c_reg = cn;
        float hn = og * tanh_(cn);
        s_hh[bi] = hn;
        p.out[((size_t)(G * 16 + b) * 512 + t) * 512 + jt * 16 + jj] = hn;
      }
      __syncthreads();
      if (tid < 128) {                              // pack h -> frag layout
        int b = tid >> 3, jp = tid & 7;
        int c = jt * 16 + jp * 2;
        int kc = c >> 5, qd = (c >> 3) & 3, e2 = (c & 7) >> 1;
        int dw = ((G * 16 + kc) * 4 + qd) * 64 + b * 4 + e2;
        stcg_u(&p.hrep[dw], pk(s_hh[b * 16 + jp * 2], s_hh[b * 16 + jp * 2 + 1]));
      }
    }
    sync_bar(gbar, (unsigned)(w6 & 7), 7u, dead);         // GROUP (D -> A)
  }
}

// ===========================================================================
extern "C" void kernel_launch(void* const* d_in, const int* in_sizes, int n_in,
                              void* d_out, int out_size, void* d_ws, size_t ws_size,
                              hipStream_t stream) {
  (void)in_sizes; (void)n_in; (void)out_size;
  const float* hv   = (const float*)d_in[0];
  const float* hs   = (const float*)d_in[1];
  const float* W_S  = (const float*)d_in[2];
  const float* b_S  = (const float*)d_in[3];
  const float* W_V  = (const float*)d_in[4];
  const float* b_V  = (const float*)d_in[5];
  const float* W_R  = (const float*)d_in[6];
  const float* b_R  = (const float*)d_in[7];
  const float* W_w  = (const float*)d_in[8];
  /* d_in[9] = b_w: dropped (softmax shift-invariance) */
  const float* W_ih = (const float*)d_in[10];
  const float* b_ih = (const float*)d_in[11];
  const float* W_hh = (const float*)d_in[12];
  const float* b_hh = (const float*)d_in[13];

  char* ws = (char*)d_ws;
  unsigned long long off = 0;
  auto alloc = [&](unsigned long long bytes) {
    unsigned long long pp = off; off += (bytes + 255ull) & ~255ull; return pp;
  };
  ushort_t* Sproj = (ushort_t*)(ws + alloc(5120ull * 512 * 2));
  ushort_t* Vproj = (ushort_t*)(ws + alloc(512ull * 64 * 512 * 2));   // time-major
  ushort_t* hsb   = (ushort_t*)(ws + alloc(64ull * 80 * 512 * 2));
  ushort_t* WRf   = (ushort_t*)(ws + alloc(512ull * 512 * 2));
  ushort_t* Whhf  = (ushort_t*)(ws + alloc(2048ull * 512 * 2));
  ushort_t* Wqf   = (ushort_t*)(ws + alloc(2048ull * 512 * 2));
  float*    ru    = (float*)(ws + alloc(64ull * 512 * 4));
  float*    expb  = (float*)(ws + alloc(2ull * 64 * 80 * 4));
  unsigned long long zoff = off;
  uint_t*   hrep  = (uint_t*)(ws + alloc(16384ull * 4));
  uint_t*   hsrep = (uint_t*)(ws + alloc(16384ull * 4));
  float*    s4    = (float*)(ws + alloc(3ull * 320 * 4));
  unsigned* bar   = (unsigned*)(ws + alloc(16384));
  unsigned long long zsize = off - zoff;
  unsigned long long tail = off;                    // Xproj or Wihf goes here
  bool precX = ws_size >= tail + 512ull * 64 * 2048 * 2 + 4096;
  ushort_t* Xproj = precX ? (ushort_t*)(ws + tail) : nullptr;
  ushort_t* Wihf  = precX ? nullptr : (ushort_t*)(ws + tail);

  cvt_kernel<<<2560, 256, 0, stream>>>(hs, hsb, 64 * 80 * 512 / 4);
  pack_frag_kernel<<<128, 256, 0, stream>>>(W_R,  512,  0,    WRf,  0, 4);
  pack_frag_kernel<<<512, 256, 0, stream>>>(W_hh, 512,  0,    Whhf, 1, 4);
  pack_frag_kernel<<<512, 256, 0, stream>>>(W_ih, 1536, 1024, Wqf,  1, 4);
  if (!precX)
    pack_frag_kernel<<<1024, 256, 0, stream>>>(W_ih, 1536, 0, Wihf, 1, 5);

  // S_proj = h_s.W_S^T + b_S            (5120 x 512, K=512), row-major
  gemm_bt<<<dim3(4, 40), 256, 0, stream>>>(hs, 512, W_S, 512, b_S, Sproj, 512, 512, 0);
  // V_proj = h_v.W_V^T + b_V            (32768 x 512, K=1024), time-major
  gemm_bt<<<dim3(4, 256), 256, 0, stream>>>(hv, 1024, W_V, 1024, b_V, Vproj, 512, 1024, 1);
  // Xproj = h_v.(W_ih[:, :1024])^T      (32768 x 2048, K=1024), time-major
  if (precX)
    gemm_bt<<<dim3(16, 256), 256, 0, stream>>>(hv, 1024, W_ih, 1536, nullptr, Xproj, 2048, 1024, 1);

  hipMemsetAsync(ws + zoff, 0, (size_t)zsize, stream);   // hrep/hsrep/s4/bar = 0

  LoopArgs la;
  la.Sproj = Sproj; la.Vproj = Vproj; la.Xproj = Xproj;
  la.WRf = WRf; la.Whhf = Whhf; la.Wqf = Wqf; la.Wihf = Wihf;
  la.hsb = hsb;
  la.bR = b_R; la.Ww = W_w; la.bih = b_ih; la.bhh = b_hh; la.hv = hv;
  la.ru = ru; la.expb = expb; la.s4 = s4;
  la.hrep = hrep; la.hsrep = hsrep; la.bar = bar; la.out = (float*)d_out;
  loop_kernel<<<256, 512, 0, stream>>>(la);
}

// Round 6
// 10173.771 us; speedup vs baseline: 2.3707x; 1.0948x over previous
//
#include <hip/hip_runtime.h>

// ============================================================================
// Interactor (attention-gated LSTM), MI355X gfx950. FP32 I/O; bf16 MFMA inside.
// Round 9: handoff-latency diet.
//  - ZERO barriers: all cross-block sync is monotonic P2P counters
//      rcnt[G]  (32 gate blocks publish ru at A;   thr 32(t+1))
//      cnt[n]   (64 b4-adds per n at B;            thr 64(t+1), per-lane poll)
//      hscnt[G] (64 blocks publish Hs frag at C;   thr 64(t+1))
//      hwcnt[G] (32 gate blocks publish h at D;    thr 32(t+1))
//    No release broadcast / reset / gen-flip; releases ride the data.
//  - ru fused into gate Phase A (+2 MFMA/wave + LDS 8-partial reduce):
//    one fewer cross-block handoff; dedicated ru blocks removed.
//  - t-invariant Sproj (20KB) & hsb (20KB) slices cached in LDS pre-loop.
//  - Xproj/Vproj prefetch issued BEFORE the A poll (HBM latency under wait).
// Ordering: every producer __syncthreads-drains (vmcnt->MALL ack) before its
// counter bump; consumer poll transitively orders all needed stores. s4 uses
// 3-parity (zeroed at C after poll), expb 2-parity (chain-verified).
// Bounded spins + sticky dead flag: a sync bug => passed:false, never a hang.
// ============================================================================

typedef unsigned short ushort_t;
typedef unsigned int uint_t;
typedef __attribute__((ext_vector_type(8))) short bf16x8;   // 8 x bf16
typedef __attribute__((ext_vector_type(4))) float f32x4;

#define MFMA_BF16 __builtin_amdgcn_mfma_f32_16x16x32_bf16

__device__ __forceinline__ float bf2f(ushort_t u) {
  return __builtin_bit_cast(float, (uint_t)u << 16);
}
__device__ __forceinline__ ushort_t f2bf(float f) {   // round-to-nearest-even
  uint_t u = __builtin_bit_cast(uint_t, f);
  u += 0x7FFFu + ((u >> 16) & 1u);
  return (ushort_t)(u >> 16);
}
__device__ __forceinline__ uint_t pk(float lo, float hi) {
  return (uint_t)f2bf(lo) | ((uint_t)f2bf(hi) << 16);
}
__device__ __forceinline__ void stage16(ushort_t* dst, const float* src) {
  float4 a = *(const float4*)src,     b = *(const float4*)(src + 4);
  float4 c = *(const float4*)(src + 8), d = *(const float4*)(src + 12);
  uint4 lo = { pk(a.x,a.y), pk(a.z,a.w), pk(b.x,b.y), pk(b.z,b.w) };
  uint4 hi = { pk(c.x,c.y), pk(c.z,c.w), pk(d.x,d.y), pk(d.z,d.w) };
  *(uint4*)dst = lo; *(uint4*)(dst + 8) = hi;
}
__device__ __forceinline__ bf16x8 cvt8(const float* src) {
  float4 a = *(const float4*)src, b = *(const float4*)(src + 4);
  uint4 u = { pk(a.x,a.y), pk(a.z,a.w), pk(b.x,b.y), pk(b.z,b.w) };
  return __builtin_bit_cast(bf16x8, u);
}
__device__ __forceinline__ float tanh_(float x) {
  float e = __expf(2.f * x);
  return 1.f - 2.f * __builtin_amdgcn_rcpf(e + 1.f);
}
__device__ __forceinline__ float sigm_(float x) {
  return __builtin_amdgcn_rcpf(1.f + __expf(-x));
}

// -------- device-coherent (MALL) accessors ---------------------------------
__device__ __forceinline__ float ldcg_f(const float* p) {
  return __hip_atomic_load(p, __ATOMIC_RELAXED, __HIP_MEMORY_SCOPE_AGENT);
}
__device__ __forceinline__ void stcg_f(float* p, float v) {
  __hip_atomic_store(p, v, __ATOMIC_RELAXED, __HIP_MEMORY_SCOPE_AGENT);
}
__device__ __forceinline__ uint_t ldcg_u(const uint_t* p) {
  return __hip_atomic_load(p, __ATOMIC_RELAXED, __HIP_MEMORY_SCOPE_AGENT);
}
__device__ __forceinline__ void stcg_u(uint_t* p, uint_t v) {
  __hip_atomic_store(p, v, __ATOMIC_RELAXED, __HIP_MEMORY_SCOPE_AGENT);
}

// fp32 -> bf16 elementwise (n4 = count of float4 groups)
__global__ __launch_bounds__(256) void cvt_kernel(
    const float* __restrict__ in, ushort_t* __restrict__ out, int n4) {
  int i = blockIdx.x * blockDim.x + threadIdx.x;
  if (i < n4) {
    float4 v = ((const float4*)in)[i];
    uint2 r = { pk(v.x, v.y), pk(v.z, v.w) };
    ((uint2*)out)[i] = r;
  }
}

// ---------------------------------------------------------------------------
// Pack weight rows into per-tile MFMA B-fragment order:
//   out[(tile*KCT + kc)*512 + lane*8 + e] = src[row*ld + coff + kc*32 + (lane>>4)*8 + e]
//   row = mode ? (tile&3)*512 + (tile>>2)*16 + (lane&15) : tile*16 + (lane&15)
// lkc = log2(KCT). One thread packs 8 elements.
// ---------------------------------------------------------------------------
__global__ __launch_bounds__(256) void pack_frag_kernel(
    const float* __restrict__ src, int ld, int coff,
    ushort_t* __restrict__ out, int mode, int lkc) {
  size_t o = ((size_t)blockIdx.x * 256 + threadIdx.x) * 8;
  int lane = (int)((o >> 3) & 63);
  int kc   = (int)((o >> 9) & ((1u << lkc) - 1u));
  int tile = (int)(o >> (9 + lkc));
  int row  = mode ? ((tile & 3) * 512 + (tile >> 2) * 16 + (lane & 15))
                  : (tile * 16 + (lane & 15));
  int col  = kc * 32 + (lane >> 4) * 8;
  const float* s = &src[(size_t)row * ld + coff + col];
  float4 a = *(const float4*)s, b = *(const float4*)(s + 4);
  uint4 u = { pk(a.x,a.y), pk(a.z,a.w), pk(b.x,b.y), pk(b.z,b.w) };
  *(uint4*)&out[o] = u;
}

// ---------------------------------------------------------------------------
// C = A*W^T (+bias), A:[MxK] fp32 (lda), W:[NxK] fp32 (ldw), out bf16 [..xldo].
// tmaj: output row remap row -> (row&511)*64 + (row>>9)  (time-major (t,b)).
// ---------------------------------------------------------------------------
__global__ __launch_bounds__(256) void gemm_bt(
    const float* __restrict__ A, int lda,
    const float* __restrict__ W, int ldw,
    const float* __restrict__ bias1,
    ushort_t* __restrict__ out, int ldo, int K, int tmaj)
{
  __shared__ __align__(16) ushort_t sA[128][32];
  __shared__ __align__(16) ushort_t sW[128][32];
  const int tid = threadIdx.x;
  const int col0 = blockIdx.x * 128, row0 = blockIdx.y * 128;
  const int lane = tid & 63, wv = tid >> 6;
  const int wr = (wv & 1) * 64, wc = (wv >> 1) * 64;
  const int fr = lane & 15, quad = lane >> 4;
  const int sr = tid >> 1, skk = (tid & 1) * 16;
  f32x4 acc[4][4] = {};
  for (int k0 = 0; k0 < K; k0 += 32) {
    stage16(&sA[sr][skk], &A[(size_t)(row0 + sr) * lda + k0 + skk]);
    stage16(&sW[sr][skk], &W[(size_t)(col0 + sr) * ldw + k0 + skk]);
    __syncthreads();
    bf16x8 af[4], wf[4];
    #pragma unroll
    for (int mt = 0; mt < 4; ++mt) af[mt] = *(const bf16x8*)&sA[wr + mt*16 + fr][quad*8];
    #pragma unroll
    for (int nt = 0; nt < 4; ++nt) wf[nt] = *(const bf16x8*)&sW[wc + nt*16 + fr][quad*8];
    #pragma unroll
    for (int mt = 0; mt < 4; ++mt)
      #pragma unroll
      for (int nt = 0; nt < 4; ++nt)
        acc[mt][nt] = MFMA_BF16(af[mt], wf[nt], acc[mt][nt], 0, 0, 0);
    __syncthreads();
  }
  #pragma unroll
  for (int nt = 0; nt < 4; ++nt) {
    int col = col0 + wc + nt*16 + fr;
    float bs = bias1 ? bias1[col] : 0.f;
    #pragma unroll
    for (int mt = 0; mt < 4; ++mt)
      #pragma unroll
      for (int r = 0; r < 4; ++r) {
        int row = row0 + wr + mt*16 + quad*4 + r;
        int orow = tmaj ? ((row & 511) * 64 + (row >> 9)) : row;
        out[(size_t)orow * ldo + col] = f2bf(acc[mt][nt][r] + bs);
      }
  }
}

// ---------------------------------------------------------------------------
// Bounded monotonic-counter wait: spin until *c >= thr (wrap-safe), with
// sticky dead flag so a sync bug can never hang the device.
// ---------------------------------------------------------------------------
__device__ __forceinline__ void spin_ge(unsigned* c, unsigned thr, unsigned* dead) {
  int n = 0;
  while ((int)(__hip_atomic_load(c, __ATOMIC_RELAXED, __HIP_MEMORY_SCOPE_AGENT) - thr) < 0) {
    __builtin_amdgcn_s_sleep(2);
    if (++n > 30000) {
      stcg_u(dead, 1u);
      break;
    }
    if ((n & 15) == 0 && ldcg_u(dead) != 0u) break;
  }
}

struct LoopArgs {
  const ushort_t *Sproj, *Vproj, *Xproj;            // precomputed bf16
  const ushort_t *WRf, *Whhf, *Wqf, *Wihf;          // frag-packed bf16 weights
  const ushort_t *hsb;                              // bf16 h_s
  const float *bR, *Ww, *bih, *bhh, *hv;            // fp32 inputs
  float *ru, *expb, *s4;                            // cross-block scratch
  uint_t *hrep, *hsrep;                             // h / Hs in MFMA-frag dwords
  unsigned *bar;
  float *out;                                       // (B,T,HI) fp32
};

// frag dword layout for a 64x512 bf16 matrix (h, Hs):
//   element (row r, col c): mt=r>>4, kc=c>>5, quad=(c>>3)&3, e=c&7
//   dword = ((mt*16+kc)*4+quad)*64 + (r&15)*4 + (e>>1); per-mt slice = 16 KB.
// bar (dwords): rcnt[G]=G*32, hscnt[G]=128+G*32, hwcnt[G]=256+G*32,
//   cnt[n]=512+n*32 (n<80), dead=3584.

// 256 blocks x 512 threads, persistent over T=512 steps. 4 groups of 64:
// w6<32 = gate blocks (A: hh+ru MFMA, B, C, D); w6>=32 = beta blocks (B, C).
__global__ __launch_bounds__(512, 2) void loop_kernel(LoopArgs p) {
  const int blk = blockIdx.x, tid = threadIdx.x;
  const int lane = tid & 63, wv = tid >> 6;
  const int fr = lane & 15, quad = lane >> 4;
  const int G = blk >> 6, w6 = blk & 63;
  const int b4 = G * 16 + (w6 & 15), q = w6 >> 4;   // beta/C role (all blocks)
  const bool isGate = (w6 < 32);
  const int jt = w6 & 31;                           // gate j-tile (and ru tile)
  const int g = wv & 3, kh = wv >> 2;               // gate wave roles

  unsigned* dead  = p.bar + 3584;
  unsigned* rcnt  = p.bar + G * 32;
  unsigned* hscnt = p.bar + 128 + G * 32;
  unsigned* hwcnt = p.bar + 256 + G * 32;
  unsigned* cnt0  = p.bar + 512;                    // + n*32

  __shared__ __align__(16) uint_t sH[4096];         // 16 KB staged frag slice
  __shared__ __align__(16) float s_ru[512];
  __shared__ __align__(16) float s_ww[512];
  __shared__ __align__(16) float s_red[512];
  __shared__ __align__(16) float s_acc[8][256];
  __shared__ __align__(16) ushort_t sSp[20][512];   // Sproj slice (t-invariant)
  __shared__ __align__(16) ushort_t sHsb[80][128];  // hsb slice  (t-invariant)
  __shared__ float s_hsv[128];
  __shared__ float s_alpha[80];
  __shared__ float s_hh[256];
  __shared__ float s_bias[64];

  s_ww[tid] = p.Ww[tid];
  if (isGate && tid < 64) {
    int n = (tid >> 4) * 512 + jt * 16 + (tid & 15);
    s_bias[tid] = p.bih[n] + p.bhh[n];
  }
  float brv = 0.f;
  if (isGate && tid < 256) brv = p.bR[jt * 16 + (tid & 15)];
  // t-invariant LDS caches
  for (int i = tid; i < 1280; i += 512) {           // sSp: 20 x 512 bf16
    int nl = i >> 6, c8 = (i & 63) * 8;
    *(uint4*)&sSp[nl][c8] =
        *(const uint4*)&p.Sproj[((size_t)(b4 * 80 + q * 20 + nl)) * 512 + c8];
  }
  for (int i = tid; i < 1280; i += 512) {           // sHsb: 80 x 128 bf16
    int n = i >> 4, c8 = (i & 15) * 8;
    *(uint4*)&sHsb[n][c8] =
        *(const uint4*)&p.hsb[(size_t)b4 * 40960 + (size_t)n * 512 + q * 128 + c8];
  }
  float c_reg = 0.f;

  // ---- loop-invariant weight fragments in VGPRs ---------------------------
  bf16x8 wf2[16];                                   // gate: Whh / Wq halves
  bf16x8 wfR[2];                                    // gate: WR (ru slice)
  bf16x8 wfx[16];                                   // gate fallback (in-loop X)
  if (isGate) {
    #pragma unroll
    for (int kc = 0; kc < 8; ++kc) {
      int kcg = kh * 8 + kc;
      wf2[kc]     = *(const bf16x8*)&p.Whhf[((size_t)(jt*4+g)*16 + kcg)*512 + lane*8];
      wf2[8 + kc] = *(const bf16x8*)&p.Wqf [((size_t)(jt*4+g)*16 + kcg)*512 + lane*8];
    }
    #pragma unroll
    for (int i = 0; i < 2; ++i)
      wfR[i] = *(const bf16x8*)&p.WRf[((size_t)jt*16 + wv*2 + i)*512 + lane*8];
    if (!p.Xproj) {
      #pragma unroll
      for (int kc = 0; kc < 16; ++kc)
        wfx[kc] = *(const bf16x8*)&p.Wihf[((size_t)(jt*4+g)*32 + kh*16 + kc)*512 + lane*8];
    }
  }
  __syncthreads();

  f32x4 accA = {};
  for (int t = 0; t < 512; ++t) {
    float x0 = 0.f, x1 = 0.f, x2 = 0.f, x3 = 0.f, vv = 0.f;
    // ====== Phase A (gates): prefetch, h-wait, ru MFMA+publish, hh MFMA ====
    if (isGate) {
      if (tid < 256) {                              // issue BEFORE the poll
        if (p.Xproj) {
          const ushort_t* xp = &p.Xproj[(size_t)t * 131072 +
                                        (size_t)(G * 16 + (tid >> 4)) * 2048 + jt * 16 + (tid & 15)];
          x0 = bf2f(xp[0]);    x1 = bf2f(xp[512]);
          x2 = bf2f(xp[1024]); x3 = bf2f(xp[1536]);
        }
        vv = bf2f(p.Vproj[(size_t)t * 32768 +
                          (size_t)(G * 16 + (tid >> 4)) * 512 + jt * 16 + (tid & 15)]);
      }
      f32x4 acc = {};
      if (!p.Xproj) {                               // in-loop X fallback
        int row = G * 16 + fr;
        #pragma unroll
        for (int kc = 0; kc < 16; ++kc) {
          bf16x8 af = cvt8(&p.hv[((size_t)row * 512 + t) * 1024 + kh*512 + kc*32 + quad*8]);
          acc = MFMA_BF16(af, wfx[kc], acc, 0, 0, 0);
        }
      }
      f32x4 accR = {};
      if (t) {
        if (tid == 0) spin_ge(hwcnt, 32u * (unsigned)t, dead);
        __syncthreads();
        const uint_t* src = p.hrep + G * 4096;
        uint_t hst[8];
        #pragma unroll
        for (int i = 0; i < 8; ++i) hst[i] = ldcg_u(src + i * 512 + tid);
        #pragma unroll
        for (int i = 0; i < 8; ++i) sH[i * 512 + tid] = hst[i];
        __syncthreads();
        #pragma unroll
        for (int i = 0; i < 2; ++i) {               // ru slice first (publish asap)
          bf16x8 af = *(const bf16x8*)&sH[(wv*2 + i) * 256 + quad * 64 + fr * 4];
          accR = MFMA_BF16(af, wfR[i], accR, 0, 0, 0);
        }
      }
      #pragma unroll
      for (int r = 0; r < 4; ++r) s_acc[wv][(quad * 4 + r) * 16 + fr] = accR[r];
      __syncthreads();
      if (tid < 256) {
        float s = s_acc[0][tid] + s_acc[1][tid] + s_acc[2][tid] + s_acc[3][tid] +
                  s_acc[4][tid] + s_acc[5][tid] + s_acc[6][tid] + s_acc[7][tid] +
                  brv + vv;
        stcg_f(&p.ru[(size_t)(G * 16 + (tid >> 4)) * 512 + jt * 16 + (tid & 15)], s);
      }
      __syncthreads();                              // drain ru stores
      if (tid == 0)
        __hip_atomic_fetch_add(rcnt, 1u, __ATOMIC_RELAXED, __HIP_MEMORY_SCOPE_AGENT);
      if (t) {                                      // hh-MFMA (off handoff path)
        #pragma unroll
        for (int kc = 0; kc < 8; ++kc) {
          int kcg = kh * 8 + kc;
          bf16x8 af = *(const bf16x8*)&sH[kcg * 256 + quad * 64 + fr * 4];
          acc = MFMA_BF16(af, wf2[kc], acc, 0, 0, 0);
        }
      }
      accA = acc;                                   // lives until Phase D
    }

    // ====== Phase B (all): ru-wait, beta -> exp + s4 + cnt =================
    if (tid == 0) spin_ge(rcnt, 32u * (unsigned)(t + 1), dead);
    __syncthreads();
    s_ru[tid] = ldcg_f(&p.ru[b4 * 512 + tid]);
    __syncthreads();
    #pragma unroll
    for (int rr = 0; rr < 3; ++rr) {
      int nl = wv + 8 * rr;
      if (nl < 20) {
        int n = q * 20 + nl;
        uint4 sv = *(const uint4*)&sSp[nl][lane * 8];
        float4 r0 = *(const float4*)&s_ru[lane * 8];
        float4 r1 = *(const float4*)&s_ru[lane * 8 + 4];
        float4 w0 = *(const float4*)&s_ww[lane * 8];
        float4 w1 = *(const float4*)&s_ww[lane * 8 + 4];
        float a = 0.f;
        a += tanh_(bf2f((ushort_t)(sv.x & 0xFFFF)) + r0.x) * w0.x;
        a += tanh_(bf2f((ushort_t)(sv.x >> 16))    + r0.y) * w0.y;
        a += tanh_(bf2f((ushort_t)(sv.y & 0xFFFF)) + r0.z) * w0.z;
        a += tanh_(bf2f((ushort_t)(sv.y >> 16))    + r0.w) * w0.w;
        a += tanh_(bf2f((ushort_t)(sv.z & 0xFFFF)) + r1.x) * w1.x;
        a += tanh_(bf2f((ushort_t)(sv.z >> 16))    + r1.y) * w1.y;
        a += tanh_(bf2f((ushort_t)(sv.w & 0xFFFF)) + r1.z) * w1.z;
        a += tanh_(bf2f((ushort_t)(sv.w >> 16))    + r1.w) * w1.w;
        #pragma unroll
        for (int off = 32; off > 0; off >>= 1) a += __shfl_xor(a, off, 64);
        if (lane == 0) {
          // |beta| <= sum|W_w| ~ 8 -> exp safe without max-subtraction
          float e = __expf(a);
          stcg_f(&p.expb[(t & 1) * 5120 + n * 64 + b4], e);
          __hip_atomic_fetch_add(&p.s4[(t % 3) * 320 + G * 80 + n], e,
                                 __ATOMIC_RELAXED, __HIP_MEMORY_SCOPE_AGENT);
        }
      }
    }
    __syncthreads();                                // drain expb + s4
    if (tid < 20)
      __hip_atomic_fetch_add(cnt0 + (q * 20 + tid) * 32, 1u,
                             __ATOMIC_RELAXED, __HIP_MEMORY_SCOPE_AGENT);

    // ====== Phase C (all): per-n wait, alpha + Hs slice -> hsrep ===========
    if (tid < 80) {
      spin_ge(cnt0 + tid * 32, 64u * (unsigned)(t + 1), dead);
      const float* sc = p.s4 + (t % 3) * 320;
      float s = ldcg_f(sc + tid) + ldcg_f(sc + 80 + tid) +
                ldcg_f(sc + 160 + tid) + ldcg_f(sc + 240 + tid);
      float num = ldcg_f(&p.expb[(t & 1) * 5120 + tid * 64 + b4]);
      s_alpha[tid] = num * __builtin_amdgcn_rcpf(s);
    }
    __syncthreads();                                // all polls done
    if (blk == 0 && tid < 320)                      // zero parity t+2 (3-cycle)
      stcg_f(&p.s4[((t + 2) % 3) * 320 + tid], 0.f);
    {
      int nq = tid >> 7, jl = tid & 127;            // 4-way n-split per j
      float part = 0.f;
      #pragma unroll 5
      for (int n0 = 0; n0 < 20; ++n0) {
        int n = nq * 20 + n0;
        part += s_alpha[n] * bf2f(sHsb[n][jl]);
      }
      s_red[tid] = part;
    }
    __syncthreads();
    if (tid < 128)
      s_hsv[tid] = s_red[tid] + s_red[128 + tid] + s_red[256 + tid] + s_red[384 + tid];
    __syncthreads();
    if (tid < 64) {
      int c = q * 128 + tid * 2;
      int kc = c >> 5, qd = (c >> 3) & 3, e2 = (c & 7) >> 1;
      int dw = ((G * 16 + kc) * 4 + qd) * 64 + (b4 & 15) * 4 + e2;
      stcg_u(&p.hsrep[dw], pk(s_hsv[tid * 2], s_hsv[tid * 2 + 1]));
    }
    __syncthreads();                                // drain hsrep
    if (tid == 0)
      __hip_atomic_fetch_add(hscnt, 1u, __ATOMIC_RELAXED, __HIP_MEMORY_SCOPE_AGENT);

    // ====== Phase D (gates): Hs-wait, Hs-MFMA + gates + pointwise + h ======
    if (isGate) {
      if (tid == 0) spin_ge(hscnt, 64u * (unsigned)(t + 1), dead);
      __syncthreads();
      const uint_t* src = p.hsrep + G * 4096;
      uint_t hst[8];
      #pragma unroll
      for (int i = 0; i < 8; ++i) hst[i] = ldcg_u(src + i * 512 + tid);
      #pragma unroll
      for (int i = 0; i < 8; ++i) sH[i * 512 + tid] = hst[i];
      __syncthreads();
      f32x4 acc = accA;
      #pragma unroll
      for (int kc = 0; kc < 8; ++kc) {
        int kcg = kh * 8 + kc;
        bf16x8 af = *(const bf16x8*)&sH[kcg * 256 + quad * 64 + fr * 4];
        acc = MFMA_BF16(af, wf2[8 + kc], acc, 0, 0, 0);
      }
      #pragma unroll
      for (int r = 0; r < 4; ++r) s_acc[wv][(quad * 4 + r) * 16 + fr] = acc[r];
      __syncthreads();
      if (tid < 256) {
        int b = tid >> 4, jj = tid & 15, bi = tid;
        float g0 = s_acc[0][bi] + s_acc[4][bi] + s_bias[jj];
        float g1 = s_acc[1][bi] + s_acc[5][bi] + s_bias[16 + jj];
        float g2 = s_acc[2][bi] + s_acc[6][bi] + s_bias[32 + jj];
        float g3 = s_acc[3][bi] + s_acc[7][bi] + s_bias[48 + jj];
        g0 += x0; g1 += x1; g2 += x2; g3 += x3;
        float ig = sigm_(g0), fg = sigm_(g1), gv = tanh_(g2), og = sigm_(g3);
        float cn = fg * c_reg + ig * gv;
        c_reg = cn;
        float hn = og * tanh_(cn);
        s_hh[bi] = hn;
        p.out[((size_t)(G * 16 + b) * 512 + t) * 512 + jt * 16 + jj] = hn;
      }
      __syncthreads();
      if (tid < 128) {                              // pack h -> frag layout
        int b = tid >> 3, jp = tid & 7;
        int c = jt * 16 + jp * 2;
        int kc = c >> 5, qd = (c >> 3) & 3, e2 = (c & 7) >> 1;
        int dw = ((G * 16 + kc) * 4 + qd) * 64 + b * 4 + e2;
        stcg_u(&p.hrep[dw], pk(s_hh[b * 16 + jp * 2], s_hh[b * 16 + jp * 2 + 1]));
      }
      __syncthreads();                              // drain hrep + out
      if (tid == 0)
        __hip_atomic_fetch_add(hwcnt, 1u, __ATOMIC_RELAXED, __HIP_MEMORY_SCOPE_AGENT);
    }
  }
}

// ===========================================================================
extern "C" void kernel_launch(void* const* d_in, const int* in_sizes, int n_in,
                              void* d_out, int out_size, void* d_ws, size_t ws_size,
                              hipStream_t stream) {
  (void)in_sizes; (void)n_in; (void)out_size;
  const float* hv   = (const float*)d_in[0];
  const float* hs   = (const float*)d_in[1];
  const float* W_S  = (const float*)d_in[2];
  const float* b_S  = (const float*)d_in[3];
  const float* W_V  = (const float*)d_in[4];
  const float* b_V  = (const float*)d_in[5];
  const float* W_R  = (const float*)d_in[6];
  const float* b_R  = (const float*)d_in[7];
  const float* W_w  = (const float*)d_in[8];
  /* d_in[9] = b_w: dropped (softmax shift-invariance) */
  const float* W_ih = (const float*)d_in[10];
  const float* b_ih = (const float*)d_in[11];
  const float* W_hh = (const float*)d_in[12];
  const float* b_hh = (const float*)d_in[13];

  char* ws = (char*)d_ws;
  unsigned long long off = 0;
  auto alloc = [&](unsigned long long bytes) {
    unsigned long long pp = off; off += (bytes + 255ull) & ~255ull; return pp;
  };
  ushort_t* Sproj = (ushort_t*)(ws + alloc(5120ull * 512 * 2));
  ushort_t* Vproj = (ushort_t*)(ws + alloc(512ull * 64 * 512 * 2));   // time-major
  ushort_t* hsb   = (ushort_t*)(ws + alloc(64ull * 80 * 512 * 2));
  ushort_t* WRf   = (ushort_t*)(ws + alloc(512ull * 512 * 2));
  ushort_t* Whhf  = (ushort_t*)(ws + alloc(2048ull * 512 * 2));
  ushort_t* Wqf   = (ushort_t*)(ws + alloc(2048ull * 512 * 2));
  float*    ru    = (float*)(ws + alloc(64ull * 512 * 4));
  float*    expb  = (float*)(ws + alloc(2ull * 64 * 80 * 4));
  unsigned long long zoff = off;
  uint_t*   hrep  = (uint_t*)(ws + alloc(16384ull * 4));
  uint_t*   hsrep = (uint_t*)(ws + alloc(16384ull * 4));
  float*    s4    = (float*)(ws + alloc(3ull * 320 * 4));
  unsigned* bar   = (unsigned*)(ws + alloc(16384));
  unsigned long long zsize = off - zoff;
  unsigned long long tail = off;                    // Xproj or Wihf goes here
  bool precX = ws_size >= tail + 512ull * 64 * 2048 * 2 + 4096;
  ushort_t* Xproj = precX ? (ushort_t*)(ws + tail) : nullptr;
  ushort_t* Wihf  = precX ? nullptr : (ushort_t*)(ws + tail);

  cvt_kernel<<<2560, 256, 0, stream>>>(hs, hsb, 64 * 80 * 512 / 4);
  pack_frag_kernel<<<128, 256, 0, stream>>>(W_R,  512,  0,    WRf,  0, 4);
  pack_frag_kernel<<<512, 256, 0, stream>>>(W_hh, 512,  0,    Whhf, 1, 4);
  pack_frag_kernel<<<512, 256, 0, stream>>>(W_ih, 1536, 1024, Wqf,  1, 4);
  if (!precX)
    pack_frag_kernel<<<1024, 256, 0, stream>>>(W_ih, 1536, 0, Wihf, 1, 5);

  // S_proj = h_s.W_S^T + b_S            (5120 x 512, K=512), row-major
  gemm_bt<<<dim3(4, 40), 256, 0, stream>>>(hs, 512, W_S, 512, b_S, Sproj, 512, 512, 0);
  // V_proj = h_v.W_V^T + b_V            (32768 x 512, K=1024), time-major
  gemm_bt<<<dim3(4, 256), 256, 0, stream>>>(hv, 1024, W_V, 1024, b_V, Vproj, 512, 1024, 1);
  // Xproj = h_v.(W_ih[:, :1024])^T      (32768 x 2048, K=1024), time-major
  if (precX)
    gemm_bt<<<dim3(16, 256), 256, 0, stream>>>(hv, 1024, W_ih, 1536, nullptr, Xproj, 2048, 1024, 1);

  hipMemsetAsync(ws + zoff, 0, (size_t)zsize, stream);   // hrep/hsrep/s4/bar = 0

  LoopArgs la;
  la.Sproj = Sproj; la.Vproj = Vproj; la.Xproj = Xproj;
  la.WRf = WRf; la.Whhf = Whhf; la.Wqf = Wqf; la.Wihf = Wihf;
  la.hsb = hsb;
  la.bR = b_R; la.Ww = W_w; la.bih = b_ih; la.bhh = b_hh; la.hv = hv;
  la.ru = ru; la.expb = expb; la.s4 = s4;
  la.hrep = hrep; la.hsrep = hsrep; la.bar = bar; la.out = (float*)d_out;
  loop_kernel<<<256, 512, 0, stream>>>(la);
}